// Round 3
// baseline (343.721 us; speedup 1.0000x reference)
//
#include <hip/hip_runtime.h>
#include <math.h>

typedef unsigned short u16x8 __attribute__((ext_vector_type(8)));
typedef unsigned short u16x2 __attribute__((ext_vector_type(2)));
typedef short s16x8 __attribute__((ext_vector_type(8)));
typedef float f32x4 __attribute__((ext_vector_type(4)));

__device__ __forceinline__ float bf2f(unsigned short u) {
    union { unsigned int i; float f; } v; v.i = ((unsigned int)u) << 16; return v.f;
}
__device__ __forceinline__ unsigned short f2bf(float f) {
    union { unsigned int i; float f; } v; v.f = f;
    unsigned int r = v.i + 0x7FFFu + ((v.i >> 16) & 1u);
    return (unsigned short)(r >> 16);
}

// ---------------- workspace layout (bytes) ----------------
#define MATS_OFF 16384
#define WB_OFF   548864
#define STAT_OFF 942080
#define Y_OFF    1048576
#define YT_OFF   34603008
#define Z_OFF    Y_OFF

// ============ kernel 1: merged prep — S4D matrix precompute (blocks 0..127),
// conv-weight bf16 pack (blocks 128..895), stats zero-init (block 128) ============
__global__ void prep(const float* __restrict__ log_dt,
                     const float* __restrict__ A_log,
                     const float* __restrict__ A_imag,
                     const float* __restrict__ B_re,
                     const float* __restrict__ B_im,
                     const float* __restrict__ C_re,
                     const float* __restrict__ C_im,
                     float* __restrict__ w32,
                     unsigned short* __restrict__ MATS,
                     const float* __restrict__ w1, const float* __restrict__ w2,
                     const float* __restrict__ w3, const float* __restrict__ w4,
                     unsigned short* __restrict__ WB,
                     float* __restrict__ stats)
{
    const int tid = threadIdx.x;
    if (blockIdx.x >= 128) {
        // ---- wpack path ----
        if (blockIdx.x == 128) {
            // zero the BN stats accumulator (512 ch x {s1,s2})
            ((float4*)stats)[tid] = make_float4(0.f, 0.f, 0.f, 0.f);
        }
        int idx = (blockIdx.x - 128) * 256 + tid;
        int br = idx / 49152;
        int r  = idx - br * 49152;
        int co = r / 384;
        int k  = r - co * 384;
        int tap = k >> 7, h = k & 127;
        const float* wp = (br == 0) ? w1 : (br == 1) ? w2 : (br == 2) ? w3 : w4;
        WB[idx] = f2bf(wp[co * 384 + h * 3 + tap]);
        return;
    }
    const int h = blockIdx.x;
    const double dt = exp((double)log_dt[h]);

    #pragma unroll 1
    for (int it = 0; it < 4; it++) {
        int idx = tid + (it << 8);
        int s = idx >> 5, i = idx & 31;
        int n = s >> 1;
        double Ar = -exp((double)A_log[h * 16 + n]);
        double Ai = (double)A_imag[h * 16 + n];
        double dr = dt * Ar, di = dt * Ai;
        double l = (double)(31 - i);
        double e = exp(l * dr);
        double val = (s & 1) ? e * sin(l * di) : e * cos(l * di);
        MATS[(size_t)h * 2080 + s * 32 + i] = f2bf((float)val);
    }
    #pragma unroll 1
    for (int it = 0; it < 4; it++) {
        int idx = tid + (it << 8);
        int j = idx >> 5, s = idx & 31;
        int n = s >> 1;
        double Ar = -exp((double)A_log[h * 16 + n]);
        double Ai = (double)A_imag[h * 16 + n];
        double dr = dt * Ar, di = dt * Ai;
        double ew = exp(dr);
        double wr = ew * cos(di), wi = ew * sin(di);
        double nr = wr - 1.0, ni = wi;
        double inv = 1.0 / (Ar * Ar + Ai * Ai);
        double tr = (nr * Ar + ni * Ai) * inv;
        double ti = (ni * Ar - nr * Ai) * inv;
        double Br = (double)B_re[h * 16 + n], Bi = (double)B_im[h * 16 + n];
        double dbr = tr * Br - ti * Bi, dbi = tr * Bi + ti * Br;
        double Cr = (double)C_re[h * 16 + n], Ci = (double)C_im[h * 16 + n];
        double cbr = Cr * dbr - Ci * dbi, cbi = Cr * dbi + Ci * dbr;
        double m = (double)(j + 1);
        double e = exp(m * dr);
        double pr = e * cos(m * di), pi = e * sin(m * di);
        double gr = cbr * pr - cbi * pi, gi = cbr * pi + cbi * pr;
        double val = (s & 1) ? -2.0 * gi : 2.0 * gr;
        MATS[(size_t)h * 2080 + 1024 + j * 32 + s] = f2bf((float)val);
    }
    {
        int l = tid >> 3, sub = tid & 7;
        double accd = 0.0;
        #pragma unroll 1
        for (int q = 0; q < 2; q++) {
            int n = sub * 2 + q;
            double Ar = -exp((double)A_log[h * 16 + n]);
            double Ai = (double)A_imag[h * 16 + n];
            double dr = dt * Ar, di = dt * Ai;
            double ew = exp(dr);
            double wr = ew * cos(di), wi = ew * sin(di);
            double nr = wr - 1.0, ni = wi;
            double inv = 1.0 / (Ar * Ar + Ai * Ai);
            double tr = (nr * Ar + ni * Ai) * inv;
            double ti = (ni * Ar - nr * Ai) * inv;
            double Br = (double)B_re[h * 16 + n], Bi = (double)B_im[h * 16 + n];
            double dbr = tr * Br - ti * Bi, dbi = tr * Bi + ti * Br;
            double Cr = (double)C_re[h * 16 + n], Ci = (double)C_im[h * 16 + n];
            double cbr = Cr * dbr - Ci * dbi, cbi = Cr * dbi + Ci * dbr;
            double l2 = (double)l;
            double e = exp(l2 * dr);
            double wlr = e * cos(l2 * di), wli = e * sin(l2 * di);
            accd += cbr * wlr - cbi * wli;
        }
        float accf = (float)(2.0 * accd);
        #pragma unroll
        for (int o = 4; o > 0; o >>= 1) accf += __shfl_down(accf, o, 8);
        if (sub == 0) MATS[(size_t)h * 2080 + 2048 + l] = f2bf(accf);
    }
    if (tid < 16) {
        int n = tid;
        double Ar = -exp((double)A_log[h * 16 + n]);
        double Ai = (double)A_imag[h * 16 + n];
        double dr = dt * Ar, di = dt * Ai;
        double e = exp(32.0 * dr);
        w32[h * 32 + 2 * n]     = (float)(e * cos(32.0 * di));
        w32[h * 32 + 2 * n + 1] = (float)(e * sin(32.0 * di));
    }
}

// ============ kernel 2: S4D — MFMA chunk matmuls + shuffle carry scan ============
// LDS cut 62->50 KB (scratch transpose split into two 16-row passes) -> 3 blocks/CU.
__global__ __launch_bounds__(256, 3) void s4d_mfma(const float* __restrict__ x,
                                                   const float* __restrict__ w32,
                                                   const unsigned short* __restrict__ MATS,
                                                   const float* __restrict__ Dp,
                                                   unsigned short* __restrict__ yout)
{
    __shared__ unsigned short sXc[256 * 40];
    __shared__ unsigned short sM[3840];        // V @0, TK @1280, G @2560 (stride 40)
    __shared__ float spow2[256];               // w32^(2^k), k=0..7
    __shared__ unsigned short skr[32];
    __shared__ float swc[128];                 // cross-wave carries 4x32
    __shared__ float scratch[5120];            // 16 x 260 unpack buffer / sCc u16 (20.5 KB)
    const int tid = threadIdx.x;
    const int bh = blockIdx.x;
    const int h = bh & 127;
    const int lane = tid & 63, w = tid >> 6;
    const int ml = lane & 15, kg = lane >> 4;

    float xr[32];
    const float4* xp4 = (const float4*)(x + ((size_t)bh << 13) + (tid << 5));
    #pragma unroll
    for (int i = 0; i < 8; i++) {
        float4 v = xp4[i];
        xr[4 * i] = v.x; xr[4 * i + 1] = v.y; xr[4 * i + 2] = v.z; xr[4 * i + 3] = v.w;
    }
    #pragma unroll
    for (int g = 0; g < 4; g++) {
        u16x8 pk;
        #pragma unroll
        for (int e = 0; e < 8; e++) pk[e] = f2bf(xr[g * 8 + e]);
        *(u16x8*)&sXc[tid * 40 + g * 8] = pk;
    }
    {
        int matv = tid >> 7, r = (tid >> 2) & 31, sg = tid & 3;
        u16x8 v = *(const u16x8*)(MATS + (size_t)h * 2080 + matv * 1024 + r * 32 + sg * 8);
        *(u16x8*)&sM[matv * 2560 + r * 40 + sg * 8] = v;
    }
    if (tid < 4) {
        u16x8 v = *(const u16x8*)(MATS + (size_t)h * 2080 + 2048 + tid * 8);
        *(u16x8*)&skr[tid * 8] = v;
    }
    if (tid < 16) {
        float rr = w32[h * 32 + 2 * tid], ii = w32[h * 32 + 2 * tid + 1];
        #pragma unroll
        for (int k = 0; k < 8; k++) {
            spow2[k * 32 + 2 * tid] = rr; spow2[k * 32 + 2 * tid + 1] = ii;
            float n2r = rr * rr - ii * ii, n2i = 2.f * rr * ii;
            rr = n2r; ii = n2i;
        }
    }
    __syncthreads();
    #pragma unroll
    for (int it = 0; it < 4; it++) {
        int idx = tid + (it << 8);
        int j = idx >> 5, i = idx & 31;
        sM[1280 + j * 40 + i] = (i <= j) ? skr[j - i] : (unsigned short)0;
    }
    __syncthreads();

    // ---- E = V @ Xc ----
    f32x4 acc[2][4];
    #pragma unroll
    for (int mt = 0; mt < 2; mt++)
        #pragma unroll
        for (int nt = 0; nt < 4; nt++) acc[mt][nt] = (f32x4)(0.f);
    {
        s16x8 af[2], bfr[4];
        #pragma unroll
        for (int mt = 0; mt < 2; mt++)
            af[mt] = *(const s16x8*)&sM[(mt * 16 + ml) * 40 + kg * 8];
        #pragma unroll
        for (int nt = 0; nt < 4; nt++)
            bfr[nt] = *(const s16x8*)&sXc[(w * 64 + nt * 16 + ml) * 40 + kg * 8];
        #pragma unroll
        for (int mt = 0; mt < 2; mt++)
            #pragma unroll
            for (int nt = 0; nt < 4; nt++)
                acc[mt][nt] = __builtin_amdgcn_mfma_f32_16x16x32_bf16(af[mt], bfr[nt], acc[mt][nt], 0, 0, 0);
    }
    // ---- unpack E fragments -> per-thread zr/zi, two 16-row passes (halved scratch) ----
    float zr[16], zi[16];
    #pragma unroll 1
    for (int mt = 0; mt < 2; mt++) {
        if (mt) __syncthreads();   // wait for pass-0 reads before overwriting
        #pragma unroll
        for (int nt = 0; nt < 4; nt++)
            #pragma unroll
            for (int r = 0; r < 4; r++)
                scratch[(kg * 4 + r) * 260 + (w * 64 + nt * 16 + ml)] = acc[mt][nt][r];
        __syncthreads();
        #pragma unroll
        for (int q = 0; q < 8; q++) {
            int n = mt * 8 + q;
            zr[n] = scratch[(2 * q) * 260 + tid];
            zi[n] = scratch[(2 * q + 1) * 260 + tid];
        }
    }

    // ---- in-wave inclusive scan (shuffles) ----
    #pragma unroll 1
    for (int k = 0; k < 6; k++) {
        const int o = 1 << k;
        const bool act = lane >= o;
        #pragma unroll
        for (int n = 0; n < 16; n++) {
            float lr = __shfl(zr[n], lane - o);
            float li = __shfl(zi[n], lane - o);
            float mr = spow2[(k << 5) + 2 * n], mi = spow2[(k << 5) + 2 * n + 1];
            float nzr = fmaf(mr, lr, fmaf(-mi, li, zr[n]));
            float nzi = fmaf(mr, li, fmaf(mi, lr, zi[n]));
            zr[n] = act ? nzr : zr[n];
            zi[n] = act ? nzi : zi[n];
        }
    }
    if (lane == 63) {
        #pragma unroll
        for (int n = 0; n < 16; n++) {
            swc[w * 32 + 2 * n]     = zr[n];
            swc[w * 32 + 2 * n + 1] = zi[n];
        }
    }
    __syncthreads();
    float qr[16], qi[16];
    #pragma unroll
    for (int n = 0; n < 16; n++) { qr[n] = 0.f; qi[n] = 0.f; }
    #pragma unroll 1
    for (int a = 0; a < 3; a++) {
        if (a < w) {
            int p = w - 1 - a;
            #pragma unroll
            for (int n = 0; n < 16; n++) {
                float ar = swc[a * 32 + 2 * n], ai = swc[a * 32 + 2 * n + 1];
                float mr = 1.f, mi = 0.f;
                if (p > 0) { mr = spow2[((5 + p) << 5) + 2 * n]; mi = spow2[((5 + p) << 5) + 2 * n + 1]; }
                qr[n] = fmaf(mr, ar, fmaf(-mi, ai, qr[n]));
                qi[n] = fmaf(mr, ai, fmaf(mi, ar, qi[n]));
            }
        }
    }
    float pjr[16], pji[16];
    #pragma unroll
    for (int n = 0; n < 16; n++) { pjr[n] = 1.f; pji[n] = 0.f; }
    #pragma unroll 1
    for (int k = 0; k < 6; k++) {
        const bool bit = (lane >> k) & 1;
        #pragma unroll
        for (int n = 0; n < 16; n++) {
            float mr = spow2[(k << 5) + 2 * n], mi = spow2[(k << 5) + 2 * n + 1];
            float nr2 = pjr[n] * mr - pji[n] * mi;
            float ni2 = fmaf(pjr[n], mi, pji[n] * mr);
            pjr[n] = bit ? nr2 : pjr[n];
            pji[n] = bit ? ni2 : pji[n];
        }
    }
    #pragma unroll
    for (int n = 0; n < 16; n++) {
        float pr = __shfl(zr[n], lane - 1);
        float pi = __shfl(zi[n], lane - 1);
        pr = (lane == 0) ? 0.f : pr;
        pi = (lane == 0) ? 0.f : pi;
        zr[n] = fmaf(pjr[n], qr[n], fmaf(-pji[n], qi[n], pr));
        zi[n] = fmaf(pjr[n], qi[n], fmaf(pji[n], qr[n], pi));
    }
    {
        unsigned short* sCc = (unsigned short*)scratch;
        #pragma unroll
        for (int g = 0; g < 4; g++) {
            u16x8 pk;
            #pragma unroll
            for (int q = 0; q < 4; q++) {
                pk[2 * q]     = f2bf(zr[g * 4 + q]);
                pk[2 * q + 1] = f2bf(zi[g * 4 + q]);
            }
            *(u16x8*)&sCc[tid * 40 + g * 8] = pk;
        }
    }
    __syncthreads();

    // ---- y = TK @ Xc + G @ Cc ----
    #pragma unroll
    for (int mt = 0; mt < 2; mt++)
        #pragma unroll
        for (int nt = 0; nt < 4; nt++) acc[mt][nt] = (f32x4)(0.f);
    {
        const unsigned short* sCc = (const unsigned short*)scratch;
        s16x8 a1[2], a2[2], bfx[4], bfc[4];
        #pragma unroll
        for (int mt = 0; mt < 2; mt++) {
            a1[mt] = *(const s16x8*)&sM[1280 + (mt * 16 + ml) * 40 + kg * 8];
            a2[mt] = *(const s16x8*)&sM[2560 + (mt * 16 + ml) * 40 + kg * 8];
        }
        #pragma unroll
        for (int nt = 0; nt < 4; nt++) {
            bfx[nt] = *(const s16x8*)&sXc[(w * 64 + nt * 16 + ml) * 40 + kg * 8];
            bfc[nt] = *(const s16x8*)&sCc[(w * 64 + nt * 16 + ml) * 40 + kg * 8];
        }
        #pragma unroll
        for (int mt = 0; mt < 2; mt++)
            #pragma unroll
            for (int nt = 0; nt < 4; nt++) {
                acc[mt][nt] = __builtin_amdgcn_mfma_f32_16x16x32_bf16(a1[mt], bfx[nt], acc[mt][nt], 0, 0, 0);
                acc[mt][nt] = __builtin_amdgcn_mfma_f32_16x16x32_bf16(a2[mt], bfc[nt], acc[mt][nt], 0, 0, 0);
            }
    }
    // ---- output transpose + D-residual, two 16-row passes ----
    const float Dh = Dp[h];
    u16x8* yp = (u16x8*)(yout + ((size_t)bh << 13) + (tid << 5));
    #pragma unroll 1
    for (int mt = 0; mt < 2; mt++) {
        __syncthreads();   // prior pass reads / sCc MFMA reads done before overwrite
        #pragma unroll
        for (int nt = 0; nt < 4; nt++)
            #pragma unroll
            for (int r = 0; r < 4; r++)
                scratch[(kg * 4 + r) * 260 + (w * 64 + nt * 16 + ml)] = acc[mt][nt][r];
        __syncthreads();
        #pragma unroll
        for (int g = mt * 2; g < mt * 2 + 2; g++) {
            u16x8 pk;
            #pragma unroll
            for (int e = 0; e < 8; e++) {
                int i = g * 8 + e;
                pk[e] = f2bf(fmaf(Dh, xr[i], scratch[(i - mt * 16) * 260 + tid]));
            }
            yp[g] = pk;
        }
    }
}

// ============ kernel 3: transpose y[bh][g] -> yT[b][g][h] ============
__global__ __launch_bounds__(256) void ytrans(const unsigned short* __restrict__ y,
                                              unsigned short* __restrict__ yT)
{
    __shared__ unsigned short sT[128 * 72];
    const int b = blockIdx.y, g0 = blockIdx.x << 6;
    const int tid = threadIdx.x;
    #pragma unroll
    for (int j = 0; j < 4; j++) {
        int li = tid + (j << 8);
        int h = li >> 3, g8 = (li & 7) << 3;
        u16x8 v = *(const u16x8*)(y + (((size_t)(b * 128 + h)) << 13) + g0 + g8);
        int gp = (g8 + (((h >> 3) & 7) << 3)) & 63;
        *(u16x8*)&sT[h * 72 + gp] = v;
    }
    __syncthreads();
    #pragma unroll
    for (int j = 0; j < 4; j++) {
        int li = tid + (j << 8);
        int g = li >> 4, h8 = (li & 15) << 3;
        u16x8 o;
        #pragma unroll
        for (int e = 0; e < 8; e++) {
            int h = h8 + e;
            int gp = (g + (((h >> 3) & 7) << 3)) & 63;
            o[e] = sT[h * 72 + gp];
        }
        *(u16x8*)(yT + (((size_t)(b * 8192 + g0 + g)) << 7) + h8) = o;
    }
}

// ============ kernel 4: MFMA dilated conv + bias + LeakyReLU + fused BN stats ============
// grid (16 ttile, 4 branch, 16 b). Double-buffered LDS K-loop (T3-minimum 2-phase):
// one barrier per kc step; next-step global loads issued before MFMA (latency hidden),
// LDS writes of the prefetched tile after the MFMA cluster.
// Epilogue accumulates per-channel sum / sum-of-squares into gstats via LDS + atomics.
__global__ __launch_bounds__(256) void conv_mfma(
    const unsigned short* __restrict__ yT,
    const unsigned short* __restrict__ WB,
    const float* __restrict__ b1, const float* __restrict__ b2,
    const float* __restrict__ b3, const float* __restrict__ b4,
    unsigned short* __restrict__ z,
    float* __restrict__ gstats)
{
    __shared__ unsigned short sW[2][128 * 40];
    __shared__ unsigned short sY[2][128 * 40];
    __shared__ float sS1[128];
    __shared__ float sS2[128];
    const int tid = threadIdx.x;
    const int lane = tid & 63, w = tid >> 6;
    const int branch = blockIdx.y, b = blockIdx.z;
    const int t0 = blockIdx.x << 7;
    const int d = 1 << branch;
    const int coH = (w & 1) << 6, tH = (w >> 1) << 6;
    const int ml = lane & 15, kg = lane >> 4;

    if (tid < 128) { sS1[tid] = 0.f; sS2[tid] = 0.f; }

    f32x4 acc[4][4];
    #pragma unroll
    for (int mt = 0; mt < 4; mt++)
        #pragma unroll
        for (int nt = 0; nt < 4; nt++) acc[mt][nt] = (f32x4)(0.f);

    const unsigned short* WBb = WB + (size_t)branch * 49152;

    // staging index split: each thread handles li0 = tid and li1 = tid+256 (of 512 slots)
    const int wco0 = tid >> 2,        wkq0 = (tid & 3) << 3;
    const int wco1 = (tid + 256) >> 2, wkq1 = (tid & 3) << 3;
    // Y slots: n = li>>2, kq = (li&3)<<3  (same decomposition)

    // helper to load one Y slot for step kc
    auto loadY = [&](int li, int kc) -> u16x8 {
        const int tap = kc >> 2, hc = (kc & 3) << 5;
        const int goff = d * (tap - 1);
        int n = li >> 2, kq = (li & 3) << 3;
        int g = ((t0 + n) << 2) + goff;
        u16x8 v;
        if ((unsigned)g < 8192u) {
            v = *(const u16x8*)(yT + (((size_t)(b * 8192 + g)) << 7) + hc + kq);
        } else {
            #pragma unroll
            for (int e = 0; e < 8; e++) v[e] = 0;
        }
        return v;
    };
    auto loadW = [&](int co, int kq, int kc) -> u16x8 {
        return *(const u16x8*)(WBb + (size_t)co * 384 + (kc << 5) + kq);
    };

    // ---- prologue: stage kc=0 into buffer 0 ----
    {
        u16x8 vw0 = loadW(wco0, wkq0, 0);
        u16x8 vw1 = loadW(wco1, wkq1, 0);
        u16x8 vy0 = loadY(tid, 0);
        u16x8 vy1 = loadY(tid + 256, 0);
        *(u16x8*)&sW[0][wco0 * 40 + wkq0] = vw0;
        *(u16x8*)&sW[0][wco1 * 40 + wkq1] = vw1;
        *(u16x8*)&sY[0][(tid >> 2) * 40 + ((tid & 3) << 3)] = vy0;
        *(u16x8*)&sY[0][((tid + 256) >> 2) * 40 + ((tid & 3) << 3)] = vy1;
    }

    #pragma unroll 1
    for (int kc = 0; kc < 12; kc++) {
        const int cur = kc & 1;
        __syncthreads();   // buf[cur] staged; also protects buf[cur] from early overwrite

        // issue next-step global loads (latency hides under the MFMA cluster)
        u16x8 nw0, nw1, ny0, ny1;
        const bool more = (kc + 1 < 12);
        if (more) {
            nw0 = loadW(wco0, wkq0, kc + 1);
            nw1 = loadW(wco1, wkq1, kc + 1);
            ny0 = loadY(tid, kc + 1);
            ny1 = loadY(tid + 256, kc + 1);
        }

        // fragments + MFMA from buf[cur]
        s16x8 af[4], bfr[4];
        #pragma unroll
        for (int mt = 0; mt < 4; mt++)
            af[mt] = *(const s16x8*)&sW[cur][(coH + mt * 16 + ml) * 40 + (kg << 3)];
        #pragma unroll
        for (int nt = 0; nt < 4; nt++)
            bfr[nt] = *(const s16x8*)&sY[cur][(tH + nt * 16 + ml) * 40 + (kg << 3)];
        #pragma unroll
        for (int mt = 0; mt < 4; mt++)
            #pragma unroll
            for (int nt = 0; nt < 4; nt++)
                acc[mt][nt] = __builtin_amdgcn_mfma_f32_16x16x32_bf16(af[mt], bfr[nt], acc[mt][nt], 0, 0, 0);

        // write prefetched tile into the other buffer
        if (more) {
            *(u16x8*)&sW[cur ^ 1][wco0 * 40 + wkq0] = nw0;
            *(u16x8*)&sW[cur ^ 1][wco1 * 40 + wkq1] = nw1;
            *(u16x8*)&sY[cur ^ 1][(tid >> 2) * 40 + ((tid & 3) << 3)] = ny0;
            *(u16x8*)&sY[cur ^ 1][((tid + 256) >> 2) * 40 + ((tid & 3) << 3)] = ny1;
        }
    }

    const float* bp = (branch == 0) ? b1 : (branch == 1) ? b2 : (branch == 2) ? b3 : b4;
    #pragma unroll
    for (int mt = 0; mt < 4; mt++) {
        #pragma unroll
        for (int r = 0; r < 4; r++) {
            const int co = coH + mt * 16 + (kg << 2) + r;
            const float bb = bp[co];
            float ls1 = 0.f, ls2 = 0.f;
            #pragma unroll
            for (int nt = 0; nt < 4; nt++) {
                const int t = t0 + tH + nt * 16 + ml;
                float v = acc[mt][nt][r] + bb;
                if (branch != 0) v = (v >= 0.f) ? v : 0.3f * v;
                ls1 += v;
                ls2 = fmaf(v, v, ls2);
                z[(((size_t)((branch * 16 + b) * 128 + co)) << 11) + t] = f2bf(v);
            }
            // reduce the 16 t-lanes (ml) of this (co) within the wave
            #pragma unroll
            for (int o = 8; o > 0; o >>= 1) {
                ls1 += __shfl_down(ls1, o, 16);
                ls2 += __shfl_down(ls2, o, 16);
            }
            if (ml == 0) {
                atomicAdd(&sS1[co], ls1);
                atomicAdd(&sS2[co], ls2);
            }
        }
    }
    __syncthreads();
    if (tid < 128) {
        atomicAdd(&gstats[(((size_t)branch << 7) + tid) * 2],     sS1[tid]);
        atomicAdd(&gstats[(((size_t)branch << 7) + tid) * 2 + 1], sS2[tid]);
    }
}

// ============ kernel 5: BN affine apply (finalizes raw sums inline, fp32 out) ============
__global__ __launch_bounds__(256) void bn_apply(const unsigned short* __restrict__ z,
                                                const float* __restrict__ stats,
                                                const float* __restrict__ gam,
                                                const float* __restrict__ bet,
                                                float* __restrict__ out)
{
    const size_t idx = (((size_t)blockIdx.x << 8) + threadIdx.x) << 3;
    const int t = (int)(idx & 2047);
    const size_t bc = idx >> 11;
    const int ch = (int)(bc & 511);
    const int b = (int)(bc >> 9);
    const int branch = ch >> 7, co = ch & 127;
    const float s1 = stats[ch * 2], s2 = stats[ch * 2 + 1];
    const float m = s1 * (1.0f / 32768.0f);
    const float var = fmaf(-m, m, s2 * (1.0f / 32768.0f));
    const float inv = 1.0f / sqrtf(var + 1e-5f);
    const float ga = gam[co], be = bet[co];
    const float sc = ga * inv, sh = fmaf(-m, sc, be);
    const unsigned short* zp = z + (((size_t)((branch * 16 + b) * 128 + co)) << 11) + t;
    u16x8 v = *(const u16x8*)zp;
    float4 o0, o1;
    o0.x = fmaf(bf2f(v[0]), sc, sh); o0.y = fmaf(bf2f(v[1]), sc, sh);
    o0.z = fmaf(bf2f(v[2]), sc, sh); o0.w = fmaf(bf2f(v[3]), sc, sh);
    o1.x = fmaf(bf2f(v[4]), sc, sh); o1.y = fmaf(bf2f(v[5]), sc, sh);
    o1.z = fmaf(bf2f(v[6]), sc, sh); o1.w = fmaf(bf2f(v[7]), sc, sh);
    *(float4*)(out + idx)     = o0;
    *(float4*)(out + idx + 4) = o1;
}

extern "C" void kernel_launch(void* const* d_in, const int* in_sizes, int n_in,
                              void* d_out, int out_size, void* d_ws, size_t ws_size,
                              hipStream_t stream) {
    const float* x      = (const float*)d_in[0];
    const float* log_dt = (const float*)d_in[1];
    const float* A_log  = (const float*)d_in[2];
    const float* A_imag = (const float*)d_in[3];
    const float* B_re   = (const float*)d_in[4];
    const float* B_im   = (const float*)d_in[5];
    const float* C_re   = (const float*)d_in[6];
    const float* C_im   = (const float*)d_in[7];
    const float* Dp     = (const float*)d_in[8];
    const float* w1 = (const float*)d_in[9];
    const float* b1 = (const float*)d_in[10];
    const float* w2 = (const float*)d_in[11];
    const float* b2 = (const float*)d_in[12];
    const float* w3 = (const float*)d_in[13];
    const float* b3 = (const float*)d_in[14];
    const float* w4 = (const float*)d_in[15];
    const float* b4 = (const float*)d_in[16];
    const float* gam = (const float*)d_in[17];
    const float* bet = (const float*)d_in[18];

    float* w32p = (float*)d_ws;
    unsigned short* MATSp = (unsigned short*)((char*)d_ws + MATS_OFF);
    unsigned short* WBp = (unsigned short*)((char*)d_ws + WB_OFF);
    float* stats = (float*)((char*)d_ws + STAT_OFF);
    unsigned short* yws = (unsigned short*)((char*)d_ws + Y_OFF);
    unsigned short* yT  = (unsigned short*)((char*)d_ws + YT_OFF);
    unsigned short* zws = (unsigned short*)((char*)d_ws + Z_OFF);
    float* out = (float*)d_out;

    prep<<<dim3(896), dim3(256), 0, stream>>>(log_dt, A_log, A_imag, B_re, B_im, C_re, C_im,
                                              w32p, MATSp, w1, w2, w3, w4, WBp, stats);
    s4d_mfma<<<dim3(2048), dim3(256), 0, stream>>>(x, w32p, MATSp, Dp, yws);
    ytrans<<<dim3(128, 16), dim3(256), 0, stream>>>(yws, yT);
    conv_mfma<<<dim3(16, 4, 16), dim3(256), 0, stream>>>(yT, WBp, b1, b2, b3, b4, zws, stats);
    bn_apply<<<dim3(8192), dim3(256), 0, stream>>>(zws, stats, gam, bet, out);
}

// Round 7
// 300.865 us; speedup vs baseline: 1.1424x; 1.1424x over previous
//
#include <hip/hip_runtime.h>
#include <math.h>

typedef unsigned short u16x8 __attribute__((ext_vector_type(8)));
typedef unsigned short u16x2 __attribute__((ext_vector_type(2)));
typedef short s16x8 __attribute__((ext_vector_type(8)));
typedef float f32x4 __attribute__((ext_vector_type(4)));

__device__ __forceinline__ float bf2f(unsigned short u) {
    union { unsigned int i; float f; } v; v.i = ((unsigned int)u) << 16; return v.f;
}
__device__ __forceinline__ unsigned short f2bf(float f) {
    union { unsigned int i; float f; } v; v.f = f;
    unsigned int r = v.i + 0x7FFFu + ((v.i >> 16) & 1u);
    return (unsigned short)(r >> 16);
}

// ---------------- workspace layout (bytes) ----------------
#define MATS_OFF 16384
#define WB_OFF   548864
#define STAT_OFF 942080
#define Y_OFF    1048576
#define YT_OFF   34603008
#define Z_OFF    Y_OFF

// ============ kernel 1: merged prep — S4D matrix precompute (blocks 0..127),
// conv-weight bf16 pack (blocks 128..895), stats zero-init (block 128) ============
__global__ void prep(const float* __restrict__ log_dt,
                     const float* __restrict__ A_log,
                     const float* __restrict__ A_imag,
                     const float* __restrict__ B_re,
                     const float* __restrict__ B_im,
                     const float* __restrict__ C_re,
                     const float* __restrict__ C_im,
                     float* __restrict__ w32,
                     unsigned short* __restrict__ MATS,
                     const float* __restrict__ w1, const float* __restrict__ w2,
                     const float* __restrict__ w3, const float* __restrict__ w4,
                     unsigned short* __restrict__ WB,
                     float* __restrict__ stats)
{
    const int tid = threadIdx.x;
    if (blockIdx.x >= 128) {
        // ---- wpack path ----
        if (blockIdx.x == 128) {
            // zero the BN stats accumulator (512 ch x {s1,s2})
            ((float4*)stats)[tid] = make_float4(0.f, 0.f, 0.f, 0.f);
        }
        int idx = (blockIdx.x - 128) * 256 + tid;
        int br = idx / 49152;
        int r  = idx - br * 49152;
        int co = r / 384;
        int k  = r - co * 384;
        int tap = k >> 7, h = k & 127;
        const float* wp = (br == 0) ? w1 : (br == 1) ? w2 : (br == 2) ? w3 : w4;
        WB[idx] = f2bf(wp[co * 384 + h * 3 + tap]);
        return;
    }
    const int h = blockIdx.x;
    const double dt = exp((double)log_dt[h]);

    #pragma unroll 1
    for (int it = 0; it < 4; it++) {
        int idx = tid + (it << 8);
        int s = idx >> 5, i = idx & 31;
        int n = s >> 1;
        double Ar = -exp((double)A_log[h * 16 + n]);
        double Ai = (double)A_imag[h * 16 + n];
        double dr = dt * Ar, di = dt * Ai;
        double l = (double)(31 - i);
        double e = exp(l * dr);
        double val = (s & 1) ? e * sin(l * di) : e * cos(l * di);
        MATS[(size_t)h * 2080 + s * 32 + i] = f2bf((float)val);
    }
    #pragma unroll 1
    for (int it = 0; it < 4; it++) {
        int idx = tid + (it << 8);
        int j = idx >> 5, s = idx & 31;
        int n = s >> 1;
        double Ar = -exp((double)A_log[h * 16 + n]);
        double Ai = (double)A_imag[h * 16 + n];
        double dr = dt * Ar, di = dt * Ai;
        double ew = exp(dr);
        double wr = ew * cos(di), wi = ew * sin(di);
        double nr = wr - 1.0, ni = wi;
        double inv = 1.0 / (Ar * Ar + Ai * Ai);
        double tr = (nr * Ar + ni * Ai) * inv;
        double ti = (ni * Ar - nr * Ai) * inv;
        double Br = (double)B_re[h * 16 + n], Bi = (double)B_im[h * 16 + n];
        double dbr = tr * Br - ti * Bi, dbi = tr * Bi + ti * Br;
        double Cr = (double)C_re[h * 16 + n], Ci = (double)C_im[h * 16 + n];
        double cbr = Cr * dbr - Ci * dbi, cbi = Cr * dbi + Ci * dbr;
        double m = (double)(j + 1);
        double e = exp(m * dr);
        double pr = e * cos(m * di), pi = e * sin(m * di);
        double gr = cbr * pr - cbi * pi, gi = cbr * pi + cbi * pr;
        double val = (s & 1) ? -2.0 * gi : 2.0 * gr;
        MATS[(size_t)h * 2080 + 1024 + j * 32 + s] = f2bf((float)val);
    }
    {
        int l = tid >> 3, sub = tid & 7;
        double accd = 0.0;
        #pragma unroll 1
        for (int q = 0; q < 2; q++) {
            int n = sub * 2 + q;
            double Ar = -exp((double)A_log[h * 16 + n]);
            double Ai = (double)A_imag[h * 16 + n];
            double dr = dt * Ar, di = dt * Ai;
            double ew = exp(dr);
            double wr = ew * cos(di), wi = ew * sin(di);
            double nr = wr - 1.0, ni = wi;
            double inv = 1.0 / (Ar * Ar + Ai * Ai);
            double tr = (nr * Ar + ni * Ai) * inv;
            double ti = (ni * Ar - nr * Ai) * inv;
            double Br = (double)B_re[h * 16 + n], Bi = (double)B_im[h * 16 + n];
            double dbr = tr * Br - ti * Bi, dbi = tr * Bi + ti * Br;
            double Cr = (double)C_re[h * 16 + n], Ci = (double)C_im[h * 16 + n];
            double cbr = Cr * dbr - Ci * dbi, cbi = Cr * dbi + Ci * dbr;
            double l2 = (double)l;
            double e = exp(l2 * dr);
            double wlr = e * cos(l2 * di), wli = e * sin(l2 * di);
            accd += cbr * wlr - cbi * wli;
        }
        float accf = (float)(2.0 * accd);
        #pragma unroll
        for (int o = 4; o > 0; o >>= 1) accf += __shfl_down(accf, o, 8);
        if (sub == 0) MATS[(size_t)h * 2080 + 2048 + l] = f2bf(accf);
    }
    if (tid < 16) {
        int n = tid;
        double Ar = -exp((double)A_log[h * 16 + n]);
        double Ai = (double)A_imag[h * 16 + n];
        double dr = dt * Ar, di = dt * Ai;
        double e = exp(32.0 * dr);
        w32[h * 32 + 2 * n]     = (float)(e * cos(32.0 * di));
        w32[h * 32 + 2 * n + 1] = (float)(e * sin(32.0 * di));
    }
}

// ============ kernel 2: S4D — MFMA chunk matmuls + shuffle carry scan ============
// LDS 50 KB (two-pass scratch transpose) -> 3 blocks/CU; launch_bounds min kept at 2
// so the register allocator uses its natural ~124 VGPR (min=3 forced 84 + massive
// spill: WRITE_SIZE 32->272 MB, dur 72->150 us — round-3 lesson).
__global__ __launch_bounds__(256, 2) void s4d_mfma(const float* __restrict__ x,
                                                   const float* __restrict__ w32,
                                                   const unsigned short* __restrict__ MATS,
                                                   const float* __restrict__ Dp,
                                                   unsigned short* __restrict__ yout)
{
    __shared__ unsigned short sXc[256 * 40];
    __shared__ unsigned short sM[3840];        // V @0, TK @1280, G @2560 (stride 40)
    __shared__ float spow2[256];               // w32^(2^k), k=0..7
    __shared__ unsigned short skr[32];
    __shared__ float swc[128];                 // cross-wave carries 4x32
    __shared__ float scratch[5120];            // 16 x 260 unpack buffer / sCc u16 (20.5 KB)
    const int tid = threadIdx.x;
    const int bh = blockIdx.x;
    const int h = bh & 127;
    const int lane = tid & 63, w = tid >> 6;
    const int ml = lane & 15, kg = lane >> 4;

    float xr[32];
    const float4* xp4 = (const float4*)(x + ((size_t)bh << 13) + (tid << 5));
    #pragma unroll
    for (int i = 0; i < 8; i++) {
        float4 v = xp4[i];
        xr[4 * i] = v.x; xr[4 * i + 1] = v.y; xr[4 * i + 2] = v.z; xr[4 * i + 3] = v.w;
    }
    #pragma unroll
    for (int g = 0; g < 4; g++) {
        u16x8 pk;
        #pragma unroll
        for (int e = 0; e < 8; e++) pk[e] = f2bf(xr[g * 8 + e]);
        *(u16x8*)&sXc[tid * 40 + g * 8] = pk;
    }
    {
        int matv = tid >> 7, r = (tid >> 2) & 31, sg = tid & 3;
        u16x8 v = *(const u16x8*)(MATS + (size_t)h * 2080 + matv * 1024 + r * 32 + sg * 8);
        *(u16x8*)&sM[matv * 2560 + r * 40 + sg * 8] = v;
    }
    if (tid < 4) {
        u16x8 v = *(const u16x8*)(MATS + (size_t)h * 2080 + 2048 + tid * 8);
        *(u16x8*)&skr[tid * 8] = v;
    }
    if (tid < 16) {
        float rr = w32[h * 32 + 2 * tid], ii = w32[h * 32 + 2 * tid + 1];
        #pragma unroll
        for (int k = 0; k < 8; k++) {
            spow2[k * 32 + 2 * tid] = rr; spow2[k * 32 + 2 * tid + 1] = ii;
            float n2r = rr * rr - ii * ii, n2i = 2.f * rr * ii;
            rr = n2r; ii = n2i;
        }
    }
    __syncthreads();
    #pragma unroll
    for (int it = 0; it < 4; it++) {
        int idx = tid + (it << 8);
        int j = idx >> 5, i = idx & 31;
        sM[1280 + j * 40 + i] = (i <= j) ? skr[j - i] : (unsigned short)0;
    }
    __syncthreads();

    // ---- E = V @ Xc ----
    f32x4 acc[2][4];
    #pragma unroll
    for (int mt = 0; mt < 2; mt++)
        #pragma unroll
        for (int nt = 0; nt < 4; nt++) acc[mt][nt] = (f32x4)(0.f);
    {
        s16x8 af[2], bfr[4];
        #pragma unroll
        for (int mt = 0; mt < 2; mt++)
            af[mt] = *(const s16x8*)&sM[(mt * 16 + ml) * 40 + kg * 8];
        #pragma unroll
        for (int nt = 0; nt < 4; nt++)
            bfr[nt] = *(const s16x8*)&sXc[(w * 64 + nt * 16 + ml) * 40 + kg * 8];
        #pragma unroll
        for (int mt = 0; mt < 2; mt++)
            #pragma unroll
            for (int nt = 0; nt < 4; nt++)
                acc[mt][nt] = __builtin_amdgcn_mfma_f32_16x16x32_bf16(af[mt], bfr[nt], acc[mt][nt], 0, 0, 0);
    }
    // ---- unpack E fragments -> per-thread zr/zi, two 16-row passes (halved scratch) ----
    float zr[16], zi[16];
    #pragma unroll 1
    for (int mt = 0; mt < 2; mt++) {
        if (mt) __syncthreads();   // wait for pass-0 reads before overwriting
        #pragma unroll
        for (int nt = 0; nt < 4; nt++)
            #pragma unroll
            for (int r = 0; r < 4; r++)
                scratch[(kg * 4 + r) * 260 + (w * 64 + nt * 16 + ml)] = acc[mt][nt][r];
        __syncthreads();
        #pragma unroll
        for (int q = 0; q < 8; q++) {
            int n = mt * 8 + q;
            zr[n] = scratch[(2 * q) * 260 + tid];
            zi[n] = scratch[(2 * q + 1) * 260 + tid];
        }
    }

    // ---- in-wave inclusive scan (shuffles) ----
    #pragma unroll 1
    for (int k = 0; k < 6; k++) {
        const int o = 1 << k;
        const bool act = lane >= o;
        #pragma unroll
        for (int n = 0; n < 16; n++) {
            float lr = __shfl(zr[n], lane - o);
            float li = __shfl(zi[n], lane - o);
            float mr = spow2[(k << 5) + 2 * n], mi = spow2[(k << 5) + 2 * n + 1];
            float nzr = fmaf(mr, lr, fmaf(-mi, li, zr[n]));
            float nzi = fmaf(mr, li, fmaf(mi, lr, zi[n]));
            zr[n] = act ? nzr : zr[n];
            zi[n] = act ? nzi : zi[n];
        }
    }
    if (lane == 63) {
        #pragma unroll
        for (int n = 0; n < 16; n++) {
            swc[w * 32 + 2 * n]     = zr[n];
            swc[w * 32 + 2 * n + 1] = zi[n];
        }
    }
    __syncthreads();
    float qr[16], qi[16];
    #pragma unroll
    for (int n = 0; n < 16; n++) { qr[n] = 0.f; qi[n] = 0.f; }
    #pragma unroll 1
    for (int a = 0; a < 3; a++) {
        if (a < w) {
            int p = w - 1 - a;
            #pragma unroll
            for (int n = 0; n < 16; n++) {
                float ar = swc[a * 32 + 2 * n], ai = swc[a * 32 + 2 * n + 1];
                float mr = 1.f, mi = 0.f;
                if (p > 0) { mr = spow2[((5 + p) << 5) + 2 * n]; mi = spow2[((5 + p) << 5) + 2 * n + 1]; }
                qr[n] = fmaf(mr, ar, fmaf(-mi, ai, qr[n]));
                qi[n] = fmaf(mr, ai, fmaf(mi, ar, qi[n]));
            }
        }
    }
    float pjr[16], pji[16];
    #pragma unroll
    for (int n = 0; n < 16; n++) { pjr[n] = 1.f; pji[n] = 0.f; }
    #pragma unroll 1
    for (int k = 0; k < 6; k++) {
        const bool bit = (lane >> k) & 1;
        #pragma unroll
        for (int n = 0; n < 16; n++) {
            float mr = spow2[(k << 5) + 2 * n], mi = spow2[(k << 5) + 2 * n + 1];
            float nr2 = pjr[n] * mr - pji[n] * mi;
            float ni2 = fmaf(pjr[n], mi, pji[n] * mr);
            pjr[n] = bit ? nr2 : pjr[n];
            pji[n] = bit ? ni2 : pji[n];
        }
    }
    #pragma unroll
    for (int n = 0; n < 16; n++) {
        float pr = __shfl(zr[n], lane - 1);
        float pi = __shfl(zi[n], lane - 1);
        pr = (lane == 0) ? 0.f : pr;
        pi = (lane == 0) ? 0.f : pi;
        zr[n] = fmaf(pjr[n], qr[n], fmaf(-pji[n], qi[n], pr));
        zi[n] = fmaf(pjr[n], qi[n], fmaf(pji[n], qr[n], pi));
    }
    {
        unsigned short* sCc = (unsigned short*)scratch;
        #pragma unroll
        for (int g = 0; g < 4; g++) {
            u16x8 pk;
            #pragma unroll
            for (int q = 0; q < 4; q++) {
                pk[2 * q]     = f2bf(zr[g * 4 + q]);
                pk[2 * q + 1] = f2bf(zi[g * 4 + q]);
            }
            *(u16x8*)&sCc[tid * 40 + g * 8] = pk;
        }
    }
    __syncthreads();

    // ---- y = TK @ Xc + G @ Cc ----
    #pragma unroll
    for (int mt = 0; mt < 2; mt++)
        #pragma unroll
        for (int nt = 0; nt < 4; nt++) acc[mt][nt] = (f32x4)(0.f);
    {
        const unsigned short* sCc = (const unsigned short*)scratch;
        s16x8 a1[2], a2[2], bfx[4], bfc[4];
        #pragma unroll
        for (int mt = 0; mt < 2; mt++) {
            a1[mt] = *(const s16x8*)&sM[1280 + (mt * 16 + ml) * 40 + kg * 8];
            a2[mt] = *(const s16x8*)&sM[2560 + (mt * 16 + ml) * 40 + kg * 8];
        }
        #pragma unroll
        for (int nt = 0; nt < 4; nt++) {
            bfx[nt] = *(const s16x8*)&sXc[(w * 64 + nt * 16 + ml) * 40 + kg * 8];
            bfc[nt] = *(const s16x8*)&sCc[(w * 64 + nt * 16 + ml) * 40 + kg * 8];
        }
        #pragma unroll
        for (int mt = 0; mt < 2; mt++)
            #pragma unroll
            for (int nt = 0; nt < 4; nt++) {
                acc[mt][nt] = __builtin_amdgcn_mfma_f32_16x16x32_bf16(a1[mt], bfx[nt], acc[mt][nt], 0, 0, 0);
                acc[mt][nt] = __builtin_amdgcn_mfma_f32_16x16x32_bf16(a2[mt], bfc[nt], acc[mt][nt], 0, 0, 0);
            }
    }
    // ---- output transpose + D-residual, two 16-row passes ----
    const float Dh = Dp[h];
    u16x8* yp = (u16x8*)(yout + ((size_t)bh << 13) + (tid << 5));
    #pragma unroll 1
    for (int mt = 0; mt < 2; mt++) {
        __syncthreads();   // prior pass reads / sCc MFMA reads done before overwrite
        #pragma unroll
        for (int nt = 0; nt < 4; nt++)
            #pragma unroll
            for (int r = 0; r < 4; r++)
                scratch[(kg * 4 + r) * 260 + (w * 64 + nt * 16 + ml)] = acc[mt][nt][r];
        __syncthreads();
        #pragma unroll
        for (int g = mt * 2; g < mt * 2 + 2; g++) {
            u16x8 pk;
            #pragma unroll
            for (int e = 0; e < 8; e++) {
                int i = g * 8 + e;
                pk[e] = f2bf(fmaf(Dh, xr[i], scratch[(i - mt * 16) * 260 + tid]));
            }
            yp[g] = pk;
        }
    }
}

// ============ kernel 3: transpose y[bh][g] -> yT[b][g][h] ============
__global__ __launch_bounds__(256) void ytrans(const unsigned short* __restrict__ y,
                                              unsigned short* __restrict__ yT)
{
    __shared__ unsigned short sT[128 * 72];
    const int b = blockIdx.y, g0 = blockIdx.x << 6;
    const int tid = threadIdx.x;
    #pragma unroll
    for (int j = 0; j < 4; j++) {
        int li = tid + (j << 8);
        int h = li >> 3, g8 = (li & 7) << 3;
        u16x8 v = *(const u16x8*)(y + (((size_t)(b * 128 + h)) << 13) + g0 + g8);
        int gp = (g8 + (((h >> 3) & 7) << 3)) & 63;
        *(u16x8*)&sT[h * 72 + gp] = v;
    }
    __syncthreads();
    #pragma unroll
    for (int j = 0; j < 4; j++) {
        int li = tid + (j << 8);
        int g = li >> 4, h8 = (li & 15) << 3;
        u16x8 o;
        #pragma unroll
        for (int e = 0; e < 8; e++) {
            int h = h8 + e;
            int gp = (g + (((h >> 3) & 7) << 3)) & 63;
            o[e] = sT[h * 72 + gp];
        }
        *(u16x8*)(yT + (((size_t)(b * 8192 + g0 + g)) << 7) + h8) = o;
    }
}

// ============ kernel 4: MFMA dilated conv + bias + LeakyReLU + fused BN stats ============
// grid (16 ttile, 4 branch, 16 b). Double-buffered LDS K-loop (T3-minimum 2-phase):
// one barrier per kc step; next-step global loads issued before MFMA (latency hidden),
// LDS writes of the prefetched tile after the MFMA cluster.
// Epilogue accumulates per-channel sum / sum-of-squares into gstats via LDS + atomics.
__global__ __launch_bounds__(256) void conv_mfma(
    const unsigned short* __restrict__ yT,
    const unsigned short* __restrict__ WB,
    const float* __restrict__ b1, const float* __restrict__ b2,
    const float* __restrict__ b3, const float* __restrict__ b4,
    unsigned short* __restrict__ z,
    float* __restrict__ gstats)
{
    __shared__ unsigned short sW[2][128 * 40];
    __shared__ unsigned short sY[2][128 * 40];
    __shared__ float sS1[128];
    __shared__ float sS2[128];
    const int tid = threadIdx.x;
    const int lane = tid & 63, w = tid >> 6;
    const int branch = blockIdx.y, b = blockIdx.z;
    const int t0 = blockIdx.x << 7;
    const int d = 1 << branch;
    const int coH = (w & 1) << 6, tH = (w >> 1) << 6;
    const int ml = lane & 15, kg = lane >> 4;

    if (tid < 128) { sS1[tid] = 0.f; sS2[tid] = 0.f; }

    f32x4 acc[4][4];
    #pragma unroll
    for (int mt = 0; mt < 4; mt++)
        #pragma unroll
        for (int nt = 0; nt < 4; nt++) acc[mt][nt] = (f32x4)(0.f);

    const unsigned short* WBb = WB + (size_t)branch * 49152;

    // staging index split: each thread handles li0 = tid and li1 = tid+256 (of 512 slots)
    const int wco0 = tid >> 2,        wkq0 = (tid & 3) << 3;
    const int wco1 = (tid + 256) >> 2, wkq1 = (tid & 3) << 3;
    // Y slots: n = li>>2, kq = (li&3)<<3  (same decomposition)

    // helper to load one Y slot for step kc
    auto loadY = [&](int li, int kc) -> u16x8 {
        const int tap = kc >> 2, hc = (kc & 3) << 5;
        const int goff = d * (tap - 1);
        int n = li >> 2, kq = (li & 3) << 3;
        int g = ((t0 + n) << 2) + goff;
        u16x8 v;
        if ((unsigned)g < 8192u) {
            v = *(const u16x8*)(yT + (((size_t)(b * 8192 + g)) << 7) + hc + kq);
        } else {
            #pragma unroll
            for (int e = 0; e < 8; e++) v[e] = 0;
        }
        return v;
    };
    auto loadW = [&](int co, int kq, int kc) -> u16x8 {
        return *(const u16x8*)(WBb + (size_t)co * 384 + (kc << 5) + kq);
    };

    // ---- prologue: stage kc=0 into buffer 0 ----
    {
        u16x8 vw0 = loadW(wco0, wkq0, 0);
        u16x8 vw1 = loadW(wco1, wkq1, 0);
        u16x8 vy0 = loadY(tid, 0);
        u16x8 vy1 = loadY(tid + 256, 0);
        *(u16x8*)&sW[0][wco0 * 40 + wkq0] = vw0;
        *(u16x8*)&sW[0][wco1 * 40 + wkq1] = vw1;
        *(u16x8*)&sY[0][(tid >> 2) * 40 + ((tid & 3) << 3)] = vy0;
        *(u16x8*)&sY[0][((tid + 256) >> 2) * 40 + ((tid & 3) << 3)] = vy1;
    }

    #pragma unroll 1
    for (int kc = 0; kc < 12; kc++) {
        const int cur = kc & 1;
        __syncthreads();   // buf[cur] staged; also protects buf[cur] from early overwrite

        // issue next-step global loads (latency hides under the MFMA cluster)
        u16x8 nw0, nw1, ny0, ny1;
        const bool more = (kc + 1 < 12);
        if (more) {
            nw0 = loadW(wco0, wkq0, kc + 1);
            nw1 = loadW(wco1, wkq1, kc + 1);
            ny0 = loadY(tid, kc + 1);
            ny1 = loadY(tid + 256, kc + 1);
        }

        // fragments + MFMA from buf[cur]
        s16x8 af[4], bfr[4];
        #pragma unroll
        for (int mt = 0; mt < 4; mt++)
            af[mt] = *(const s16x8*)&sW[cur][(coH + mt * 16 + ml) * 40 + (kg << 3)];
        #pragma unroll
        for (int nt = 0; nt < 4; nt++)
            bfr[nt] = *(const s16x8*)&sY[cur][(tH + nt * 16 + ml) * 40 + (kg << 3)];
        #pragma unroll
        for (int mt = 0; mt < 4; mt++)
            #pragma unroll
            for (int nt = 0; nt < 4; nt++)
                acc[mt][nt] = __builtin_amdgcn_mfma_f32_16x16x32_bf16(af[mt], bfr[nt], acc[mt][nt], 0, 0, 0);

        // write prefetched tile into the other buffer
        if (more) {
            *(u16x8*)&sW[cur ^ 1][wco0 * 40 + wkq0] = nw0;
            *(u16x8*)&sW[cur ^ 1][wco1 * 40 + wkq1] = nw1;
            *(u16x8*)&sY[cur ^ 1][(tid >> 2) * 40 + ((tid & 3) << 3)] = ny0;
            *(u16x8*)&sY[cur ^ 1][((tid + 256) >> 2) * 40 + ((tid & 3) << 3)] = ny1;
        }
    }

    const float* bp = (branch == 0) ? b1 : (branch == 1) ? b2 : (branch == 2) ? b3 : b4;
    #pragma unroll
    for (int mt = 0; mt < 4; mt++) {
        #pragma unroll
        for (int r = 0; r < 4; r++) {
            const int co = coH + mt * 16 + (kg << 2) + r;
            const float bb = bp[co];
            float ls1 = 0.f, ls2 = 0.f;
            #pragma unroll
            for (int nt = 0; nt < 4; nt++) {
                const int t = t0 + tH + nt * 16 + ml;
                float v = acc[mt][nt][r] + bb;
                if (branch != 0) v = (v >= 0.f) ? v : 0.3f * v;
                ls1 += v;
                ls2 = fmaf(v, v, ls2);
                z[(((size_t)((branch * 16 + b) * 128 + co)) << 11) + t] = f2bf(v);
            }
            // reduce the 16 t-lanes (ml) of this (co) within the wave
            #pragma unroll
            for (int o = 8; o > 0; o >>= 1) {
                ls1 += __shfl_down(ls1, o, 16);
                ls2 += __shfl_down(ls2, o, 16);
            }
            if (ml == 0) {
                atomicAdd(&sS1[co], ls1);
                atomicAdd(&sS2[co], ls2);
            }
        }
    }
    __syncthreads();
    if (tid < 128) {
        atomicAdd(&gstats[(((size_t)branch << 7) + tid) * 2],     sS1[tid]);
        atomicAdd(&gstats[(((size_t)branch << 7) + tid) * 2 + 1], sS2[tid]);
    }
}

// ============ kernel 5: BN affine apply (finalizes raw sums inline, fp32 out) ============
__global__ __launch_bounds__(256) void bn_apply(const unsigned short* __restrict__ z,
                                                const float* __restrict__ stats,
                                                const float* __restrict__ gam,
                                                const float* __restrict__ bet,
                                                float* __restrict__ out)
{
    const size_t idx = (((size_t)blockIdx.x << 8) + threadIdx.x) << 3;
    const int t = (int)(idx & 2047);
    const size_t bc = idx >> 11;
    const int ch = (int)(bc & 511);
    const int b = (int)(bc >> 9);
    const int branch = ch >> 7, co = ch & 127;
    const float s1 = stats[ch * 2], s2 = stats[ch * 2 + 1];
    const float m = s1 * (1.0f / 32768.0f);
    const float var = fmaf(-m, m, s2 * (1.0f / 32768.0f));
    const float inv = 1.0f / sqrtf(var + 1e-5f);
    const float ga = gam[co], be = bet[co];
    const float sc = ga * inv, sh = fmaf(-m, sc, be);
    const unsigned short* zp = z + (((size_t)((branch * 16 + b) * 128 + co)) << 11) + t;
    u16x8 v = *(const u16x8*)zp;
    float4 o0, o1;
    o0.x = fmaf(bf2f(v[0]), sc, sh); o0.y = fmaf(bf2f(v[1]), sc, sh);
    o0.z = fmaf(bf2f(v[2]), sc, sh); o0.w = fmaf(bf2f(v[3]), sc, sh);
    o1.x = fmaf(bf2f(v[4]), sc, sh); o1.y = fmaf(bf2f(v[5]), sc, sh);
    o1.z = fmaf(bf2f(v[6]), sc, sh); o1.w = fmaf(bf2f(v[7]), sc, sh);
    *(float4*)(out + idx)     = o0;
    *(float4*)(out + idx + 4) = o1;
}

extern "C" void kernel_launch(void* const* d_in, const int* in_sizes, int n_in,
                              void* d_out, int out_size, void* d_ws, size_t ws_size,
                              hipStream_t stream) {
    const float* x      = (const float*)d_in[0];
    const float* log_dt = (const float*)d_in[1];
    const float* A_log  = (const float*)d_in[2];
    const float* A_imag = (const float*)d_in[3];
    const float* B_re   = (const float*)d_in[4];
    const float* B_im   = (const float*)d_in[5];
    const float* C_re   = (const float*)d_in[6];
    const float* C_im   = (const float*)d_in[7];
    const float* Dp     = (const float*)d_in[8];
    const float* w1 = (const float*)d_in[9];
    const float* b1 = (const float*)d_in[10];
    const float* w2 = (const float*)d_in[11];
    const float* b2 = (const float*)d_in[12];
    const float* w3 = (const float*)d_in[13];
    const float* b3 = (const float*)d_in[14];
    const float* w4 = (const float*)d_in[15];
    const float* b4 = (const float*)d_in[16];
    const float* gam = (const float*)d_in[17];
    const float* bet = (const float*)d_in[18];

    float* w32p = (float*)d_ws;
    unsigned short* MATSp = (unsigned short*)((char*)d_ws + MATS_OFF);
    unsigned short* WBp = (unsigned short*)((char*)d_ws + WB_OFF);
    float* stats = (float*)((char*)d_ws + STAT_OFF);
    unsigned short* yws = (unsigned short*)((char*)d_ws + Y_OFF);
    unsigned short* yT  = (unsigned short*)((char*)d_ws + YT_OFF);
    unsigned short* zws = (unsigned short*)((char*)d_ws + Z_OFF);
    float* out = (float*)d_out;

    prep<<<dim3(896), dim3(256), 0, stream>>>(log_dt, A_log, A_imag, B_re, B_im, C_re, C_im,
                                              w32p, MATSp, w1, w2, w3, w4, WBp, stats);
    s4d_mfma<<<dim3(2048), dim3(256), 0, stream>>>(x, w32p, MATSp, Dp, yws);
    ytrans<<<dim3(128, 16), dim3(256), 0, stream>>>(yws, yT);
    conv_mfma<<<dim3(16, 4, 16), dim3(256), 0, stream>>>(yT, WBp, b1, b2, b3, b4, zws, stats);
    bn_apply<<<dim3(8192), dim3(256), 0, stream>>>(zws, stats, gam, bet, out);
}

// Round 9
// 264.388 us; speedup vs baseline: 1.3001x; 1.1380x over previous
//
#include <hip/hip_runtime.h>
#include <math.h>

typedef unsigned short u16x8 __attribute__((ext_vector_type(8)));
typedef unsigned short u16x2 __attribute__((ext_vector_type(2)));
typedef short s16x8 __attribute__((ext_vector_type(8)));
typedef float f32x4 __attribute__((ext_vector_type(4)));

__device__ __forceinline__ float bf2f(unsigned short u) {
    union { unsigned int i; float f; } v; v.i = ((unsigned int)u) << 16; return v.f;
}
__device__ __forceinline__ unsigned short f2bf(float f) {
    union { unsigned int i; float f; } v; v.f = f;
    unsigned int r = v.i + 0x7FFFu + ((v.i >> 16) & 1u);
    return (unsigned short)(r >> 16);
}

// ---------------- workspace layout (bytes) ----------------
#define MATS_OFF 16384
#define WB_OFF   548864
#define STAT_OFF 942080
#define Y_OFF    1048576
#define YT_OFF   34603008
#define Z_OFF    Y_OFF

// ============ kernel 1: merged prep — S4D matrix precompute (blocks 0..127),
// conv-weight bf16 pack (blocks 128..895), stats zero-init (block 128) ============
__global__ void prep(const float* __restrict__ log_dt,
                     const float* __restrict__ A_log,
                     const float* __restrict__ A_imag,
                     const float* __restrict__ B_re,
                     const float* __restrict__ B_im,
                     const float* __restrict__ C_re,
                     const float* __restrict__ C_im,
                     float* __restrict__ w32,
                     unsigned short* __restrict__ MATS,
                     const float* __restrict__ w1, const float* __restrict__ w2,
                     const float* __restrict__ w3, const float* __restrict__ w4,
                     unsigned short* __restrict__ WB,
                     float* __restrict__ stats)
{
    const int tid = threadIdx.x;
    if (blockIdx.x >= 128) {
        // ---- wpack path ----
        if (blockIdx.x == 128) {
            // zero the BN stats accumulator (512 ch x {s1,s2})
            ((float4*)stats)[tid] = make_float4(0.f, 0.f, 0.f, 0.f);
        }
        int idx = (blockIdx.x - 128) * 256 + tid;
        int br = idx / 49152;
        int r  = idx - br * 49152;
        int co = r / 384;
        int k  = r - co * 384;
        int tap = k >> 7, h = k & 127;
        const float* wp = (br == 0) ? w1 : (br == 1) ? w2 : (br == 2) ? w3 : w4;
        WB[idx] = f2bf(wp[co * 384 + h * 3 + tap]);
        return;
    }
    const int h = blockIdx.x;
    const double dt = exp((double)log_dt[h]);

    #pragma unroll 1
    for (int it = 0; it < 4; it++) {
        int idx = tid + (it << 8);
        int s = idx >> 5, i = idx & 31;
        int n = s >> 1;
        double Ar = -exp((double)A_log[h * 16 + n]);
        double Ai = (double)A_imag[h * 16 + n];
        double dr = dt * Ar, di = dt * Ai;
        double l = (double)(31 - i);
        double e = exp(l * dr);
        double val = (s & 1) ? e * sin(l * di) : e * cos(l * di);
        MATS[(size_t)h * 2080 + s * 32 + i] = f2bf((float)val);
    }
    #pragma unroll 1
    for (int it = 0; it < 4; it++) {
        int idx = tid + (it << 8);
        int j = idx >> 5, s = idx & 31;
        int n = s >> 1;
        double Ar = -exp((double)A_log[h * 16 + n]);
        double Ai = (double)A_imag[h * 16 + n];
        double dr = dt * Ar, di = dt * Ai;
        double ew = exp(dr);
        double wr = ew * cos(di), wi = ew * sin(di);
        double nr = wr - 1.0, ni = wi;
        double inv = 1.0 / (Ar * Ar + Ai * Ai);
        double tr = (nr * Ar + ni * Ai) * inv;
        double ti = (ni * Ar - nr * Ai) * inv;
        double Br = (double)B_re[h * 16 + n], Bi = (double)B_im[h * 16 + n];
        double dbr = tr * Br - ti * Bi, dbi = tr * Bi + ti * Br;
        double Cr = (double)C_re[h * 16 + n], Ci = (double)C_im[h * 16 + n];
        double cbr = Cr * dbr - Ci * dbi, cbi = Cr * dbi + Ci * dbr;
        double m = (double)(j + 1);
        double e = exp(m * dr);
        double pr = e * cos(m * di), pi = e * sin(m * di);
        double gr = cbr * pr - cbi * pi, gi = cbr * pi + cbi * pr;
        double val = (s & 1) ? -2.0 * gi : 2.0 * gr;
        MATS[(size_t)h * 2080 + 1024 + j * 32 + s] = f2bf((float)val);
    }
    {
        int l = tid >> 3, sub = tid & 7;
        double accd = 0.0;
        #pragma unroll 1
        for (int q = 0; q < 2; q++) {
            int n = sub * 2 + q;
            double Ar = -exp((double)A_log[h * 16 + n]);
            double Ai = (double)A_imag[h * 16 + n];
            double dr = dt * Ar, di = dt * Ai;
            double ew = exp(dr);
            double wr = ew * cos(di), wi = ew * sin(di);
            double nr = wr - 1.0, ni = wi;
            double inv = 1.0 / (Ar * Ar + Ai * Ai);
            double tr = (nr * Ar + ni * Ai) * inv;
            double ti = (ni * Ar - nr * Ai) * inv;
            double Br = (double)B_re[h * 16 + n], Bi = (double)B_im[h * 16 + n];
            double dbr = tr * Br - ti * Bi, dbi = tr * Bi + ti * Br;
            double Cr = (double)C_re[h * 16 + n], Ci = (double)C_im[h * 16 + n];
            double cbr = Cr * dbr - Ci * dbi, cbi = Cr * dbi + Ci * dbr;
            double l2 = (double)l;
            double e = exp(l2 * dr);
            double wlr = e * cos(l2 * di), wli = e * sin(l2 * di);
            accd += cbr * wlr - cbi * wli;
        }
        float accf = (float)(2.0 * accd);
        #pragma unroll
        for (int o = 4; o > 0; o >>= 1) accf += __shfl_down(accf, o, 8);
        if (sub == 0) MATS[(size_t)h * 2080 + 2048 + l] = f2bf(accf);
    }
    if (tid < 16) {
        int n = tid;
        double Ar = -exp((double)A_log[h * 16 + n]);
        double Ai = (double)A_imag[h * 16 + n];
        double dr = dt * Ar, di = dt * Ai;
        double e = exp(32.0 * dr);
        w32[h * 32 + 2 * n]     = (float)(e * cos(32.0 * di));
        w32[h * 32 + 2 * n + 1] = (float)(e * sin(32.0 * di));
    }
}

// ============ kernel 2: S4D — MFMA chunk matmuls + shuffle carry scan ============
// LDS 50 KB, two-pass scratch transpose with FULLY STATIC indices (round-7 lesson:
// '#pragma unroll 1' over mt made zr[mt*8+q]/acc[mt] runtime-indexed -> scratch
// spill, WRITE_SIZE 143 MB, 115 us). bounds min=2 (min=3 forced 84 VGPR + spill).
__global__ __launch_bounds__(256, 2) void s4d_mfma(const float* __restrict__ x,
                                                   const float* __restrict__ w32,
                                                   const unsigned short* __restrict__ MATS,
                                                   const float* __restrict__ Dp,
                                                   unsigned short* __restrict__ yout)
{
    __shared__ unsigned short sXc[256 * 40];
    __shared__ unsigned short sM[3840];        // V @0, TK @1280, G @2560 (stride 40)
    __shared__ float spow2[256];               // w32^(2^k), k=0..7
    __shared__ unsigned short skr[32];
    __shared__ float swc[128];                 // cross-wave carries 4x32
    __shared__ float scratch[5120];            // 16 x 260 unpack buffer / sCc u16 (20.5 KB)
    const int tid = threadIdx.x;
    const int bh = blockIdx.x;
    const int h = bh & 127;
    const int lane = tid & 63, w = tid >> 6;
    const int ml = lane & 15, kg = lane >> 4;

    float xr[32];
    const float4* xp4 = (const float4*)(x + ((size_t)bh << 13) + (tid << 5));
    #pragma unroll
    for (int i = 0; i < 8; i++) {
        float4 v = xp4[i];
        xr[4 * i] = v.x; xr[4 * i + 1] = v.y; xr[4 * i + 2] = v.z; xr[4 * i + 3] = v.w;
    }
    #pragma unroll
    for (int g = 0; g < 4; g++) {
        u16x8 pk;
        #pragma unroll
        for (int e = 0; e < 8; e++) pk[e] = f2bf(xr[g * 8 + e]);
        *(u16x8*)&sXc[tid * 40 + g * 8] = pk;
    }
    {
        int matv = tid >> 7, r = (tid >> 2) & 31, sg = tid & 3;
        u16x8 v = *(const u16x8*)(MATS + (size_t)h * 2080 + matv * 1024 + r * 32 + sg * 8);
        *(u16x8*)&sM[matv * 2560 + r * 40 + sg * 8] = v;
    }
    if (tid < 4) {
        u16x8 v = *(const u16x8*)(MATS + (size_t)h * 2080 + 2048 + tid * 8);
        *(u16x8*)&skr[tid * 8] = v;
    }
    if (tid < 16) {
        float rr = w32[h * 32 + 2 * tid], ii = w32[h * 32 + 2 * tid + 1];
        #pragma unroll
        for (int k = 0; k < 8; k++) {
            spow2[k * 32 + 2 * tid] = rr; spow2[k * 32 + 2 * tid + 1] = ii;
            float n2r = rr * rr - ii * ii, n2i = 2.f * rr * ii;
            rr = n2r; ii = n2i;
        }
    }
    __syncthreads();
    #pragma unroll
    for (int it = 0; it < 4; it++) {
        int idx = tid + (it << 8);
        int j = idx >> 5, i = idx & 31;
        sM[1280 + j * 40 + i] = (i <= j) ? skr[j - i] : (unsigned short)0;
    }
    __syncthreads();

    // ---- E = V @ Xc ----
    f32x4 acc[2][4];
    #pragma unroll
    for (int mt = 0; mt < 2; mt++)
        #pragma unroll
        for (int nt = 0; nt < 4; nt++) acc[mt][nt] = (f32x4)(0.f);
    {
        s16x8 af[2], bfr[4];
        #pragma unroll
        for (int mt = 0; mt < 2; mt++)
            af[mt] = *(const s16x8*)&sM[(mt * 16 + ml) * 40 + kg * 8];
        #pragma unroll
        for (int nt = 0; nt < 4; nt++)
            bfr[nt] = *(const s16x8*)&sXc[(w * 64 + nt * 16 + ml) * 40 + kg * 8];
        #pragma unroll
        for (int mt = 0; mt < 2; mt++)
            #pragma unroll
            for (int nt = 0; nt < 4; nt++)
                acc[mt][nt] = __builtin_amdgcn_mfma_f32_16x16x32_bf16(af[mt], bfr[nt], acc[mt][nt], 0, 0, 0);
    }
    // ---- unpack E fragments -> per-thread zr/zi, two explicit 16-row passes ----
    // (all register indices compile-time constant — no runtime mt)
    float zr[16], zi[16];
    // pass 0: acc[0] rows 0..15
    #pragma unroll
    for (int nt = 0; nt < 4; nt++)
        #pragma unroll
        for (int r = 0; r < 4; r++)
            scratch[(kg * 4 + r) * 260 + (w * 64 + nt * 16 + ml)] = acc[0][nt][r];
    __syncthreads();
    #pragma unroll
    for (int q = 0; q < 8; q++) {
        zr[q] = scratch[(2 * q) * 260 + tid];
        zi[q] = scratch[(2 * q + 1) * 260 + tid];
    }
    __syncthreads();
    // pass 1: acc[1] rows 16..31
    #pragma unroll
    for (int nt = 0; nt < 4; nt++)
        #pragma unroll
        for (int r = 0; r < 4; r++)
            scratch[(kg * 4 + r) * 260 + (w * 64 + nt * 16 + ml)] = acc[1][nt][r];
    __syncthreads();
    #pragma unroll
    for (int q = 0; q < 8; q++) {
        zr[8 + q] = scratch[(2 * q) * 260 + tid];
        zi[8 + q] = scratch[(2 * q + 1) * 260 + tid];
    }

    // ---- in-wave inclusive scan (shuffles) ----
    #pragma unroll 1
    for (int k = 0; k < 6; k++) {
        const int o = 1 << k;
        const bool act = lane >= o;
        #pragma unroll
        for (int n = 0; n < 16; n++) {
            float lr = __shfl(zr[n], lane - o);
            float li = __shfl(zi[n], lane - o);
            float mr = spow2[(k << 5) + 2 * n], mi = spow2[(k << 5) + 2 * n + 1];
            float nzr = fmaf(mr, lr, fmaf(-mi, li, zr[n]));
            float nzi = fmaf(mr, li, fmaf(mi, lr, zi[n]));
            zr[n] = act ? nzr : zr[n];
            zi[n] = act ? nzi : zi[n];
        }
    }
    if (lane == 63) {
        #pragma unroll
        for (int n = 0; n < 16; n++) {
            swc[w * 32 + 2 * n]     = zr[n];
            swc[w * 32 + 2 * n + 1] = zi[n];
        }
    }
    __syncthreads();
    float qr[16], qi[16];
    #pragma unroll
    for (int n = 0; n < 16; n++) { qr[n] = 0.f; qi[n] = 0.f; }
    #pragma unroll 1
    for (int a = 0; a < 3; a++) {
        if (a < w) {
            int p = w - 1 - a;
            #pragma unroll
            for (int n = 0; n < 16; n++) {
                float ar = swc[a * 32 + 2 * n], ai = swc[a * 32 + 2 * n + 1];
                float mr = 1.f, mi = 0.f;
                if (p > 0) { mr = spow2[((5 + p) << 5) + 2 * n]; mi = spow2[((5 + p) << 5) + 2 * n + 1]; }
                qr[n] = fmaf(mr, ar, fmaf(-mi, ai, qr[n]));
                qi[n] = fmaf(mr, ai, fmaf(mi, ar, qi[n]));
            }
        }
    }
    float pjr[16], pji[16];
    #pragma unroll
    for (int n = 0; n < 16; n++) { pjr[n] = 1.f; pji[n] = 0.f; }
    #pragma unroll 1
    for (int k = 0; k < 6; k++) {
        const bool bit = (lane >> k) & 1;
        #pragma unroll
        for (int n = 0; n < 16; n++) {
            float mr = spow2[(k << 5) + 2 * n], mi = spow2[(k << 5) + 2 * n + 1];
            float nr2 = pjr[n] * mr - pji[n] * mi;
            float ni2 = fmaf(pjr[n], mi, pji[n] * mr);
            pjr[n] = bit ? nr2 : pjr[n];
            pji[n] = bit ? ni2 : pji[n];
        }
    }
    #pragma unroll
    for (int n = 0; n < 16; n++) {
        float pr = __shfl(zr[n], lane - 1);
        float pi = __shfl(zi[n], lane - 1);
        pr = (lane == 0) ? 0.f : pr;
        pi = (lane == 0) ? 0.f : pi;
        zr[n] = fmaf(pjr[n], qr[n], fmaf(-pji[n], qi[n], pr));
        zi[n] = fmaf(pjr[n], qi[n], fmaf(pji[n], qr[n], pi));
    }
    {
        unsigned short* sCc = (unsigned short*)scratch;
        #pragma unroll
        for (int g = 0; g < 4; g++) {
            u16x8 pk;
            #pragma unroll
            for (int q = 0; q < 4; q++) {
                pk[2 * q]     = f2bf(zr[g * 4 + q]);
                pk[2 * q + 1] = f2bf(zi[g * 4 + q]);
            }
            *(u16x8*)&sCc[tid * 40 + g * 8] = pk;
        }
    }
    __syncthreads();

    // ---- y = TK @ Xc + G @ Cc ----
    #pragma unroll
    for (int mt = 0; mt < 2; mt++)
        #pragma unroll
        for (int nt = 0; nt < 4; nt++) acc[mt][nt] = (f32x4)(0.f);
    {
        const unsigned short* sCc = (const unsigned short*)scratch;
        s16x8 a1[2], a2[2], bfx[4], bfc[4];
        #pragma unroll
        for (int mt = 0; mt < 2; mt++) {
            a1[mt] = *(const s16x8*)&sM[1280 + (mt * 16 + ml) * 40 + kg * 8];
            a2[mt] = *(const s16x8*)&sM[2560 + (mt * 16 + ml) * 40 + kg * 8];
        }
        #pragma unroll
        for (int nt = 0; nt < 4; nt++) {
            bfx[nt] = *(const s16x8*)&sXc[(w * 64 + nt * 16 + ml) * 40 + kg * 8];
            bfc[nt] = *(const s16x8*)&sCc[(w * 64 + nt * 16 + ml) * 40 + kg * 8];
        }
        #pragma unroll
        for (int mt = 0; mt < 2; mt++)
            #pragma unroll
            for (int nt = 0; nt < 4; nt++) {
                acc[mt][nt] = __builtin_amdgcn_mfma_f32_16x16x32_bf16(a1[mt], bfx[nt], acc[mt][nt], 0, 0, 0);
                acc[mt][nt] = __builtin_amdgcn_mfma_f32_16x16x32_bf16(a2[mt], bfc[nt], acc[mt][nt], 0, 0, 0);
            }
    }
    // ---- output transpose + D-residual, two explicit 16-row passes (static idx) ----
    const float Dh = Dp[h];
    u16x8* yp = (u16x8*)(yout + ((size_t)bh << 13) + (tid << 5));
    // pass 0: acc[0] -> y rows 0..15 (output groups g=0,1)
    __syncthreads();   // sCc MFMA reads done before overwrite
    #pragma unroll
    for (int nt = 0; nt < 4; nt++)
        #pragma unroll
        for (int r = 0; r < 4; r++)
            scratch[(kg * 4 + r) * 260 + (w * 64 + nt * 16 + ml)] = acc[0][nt][r];
    __syncthreads();
    #pragma unroll
    for (int g = 0; g < 2; g++) {
        u16x8 pk;
        #pragma unroll
        for (int e = 0; e < 8; e++) {
            int i = g * 8 + e;
            pk[e] = f2bf(fmaf(Dh, xr[i], scratch[i * 260 + tid]));
        }
        yp[g] = pk;
    }
    // pass 1: acc[1] -> y rows 16..31 (output groups g=2,3)
    __syncthreads();
    #pragma unroll
    for (int nt = 0; nt < 4; nt++)
        #pragma unroll
        for (int r = 0; r < 4; r++)
            scratch[(kg * 4 + r) * 260 + (w * 64 + nt * 16 + ml)] = acc[1][nt][r];
    __syncthreads();
    #pragma unroll
    for (int g = 2; g < 4; g++) {
        u16x8 pk;
        #pragma unroll
        for (int e = 0; e < 8; e++) {
            int i = g * 8 + e;
            pk[e] = f2bf(fmaf(Dh, xr[i], scratch[(i - 16) * 260 + tid]));
        }
        yp[g] = pk;
    }
}

// ============ kernel 3: transpose y[bh][g] -> yT[b][g][h] ============
__global__ __launch_bounds__(256) void ytrans(const unsigned short* __restrict__ y,
                                              unsigned short* __restrict__ yT)
{
    __shared__ unsigned short sT[128 * 72];
    const int b = blockIdx.y, g0 = blockIdx.x << 6;
    const int tid = threadIdx.x;
    #pragma unroll
    for (int j = 0; j < 4; j++) {
        int li = tid + (j << 8);
        int h = li >> 3, g8 = (li & 7) << 3;
        u16x8 v = *(const u16x8*)(y + (((size_t)(b * 128 + h)) << 13) + g0 + g8);
        int gp = (g8 + (((h >> 3) & 7) << 3)) & 63;
        *(u16x8*)&sT[h * 72 + gp] = v;
    }
    __syncthreads();
    #pragma unroll
    for (int j = 0; j < 4; j++) {
        int li = tid + (j << 8);
        int g = li >> 4, h8 = (li & 15) << 3;
        u16x8 o;
        #pragma unroll
        for (int e = 0; e < 8; e++) {
            int h = h8 + e;
            int gp = (g + (((h >> 3) & 7) << 3)) & 63;
            o[e] = sT[h * 72 + gp];
        }
        *(u16x8*)(yT + (((size_t)(b * 8192 + g0 + g)) << 7) + h8) = o;
    }
}

// ============ kernel 4: MFMA dilated conv + bias + LeakyReLU + fused BN stats ============
// grid (16 ttile, 4 branch, 16 b). Double-buffered LDS K-loop (T3-minimum 2-phase):
// one barrier per kc step; next-step global loads issued before MFMA (latency hidden),
// LDS writes of the prefetched tile after the MFMA cluster.
// Epilogue accumulates per-channel sum / sum-of-squares into gstats via LDS + atomics.
__global__ __launch_bounds__(256) void conv_mfma(
    const unsigned short* __restrict__ yT,
    const unsigned short* __restrict__ WB,
    const float* __restrict__ b1, const float* __restrict__ b2,
    const float* __restrict__ b3, const float* __restrict__ b4,
    unsigned short* __restrict__ z,
    float* __restrict__ gstats)
{
    __shared__ unsigned short sW[2][128 * 40];
    __shared__ unsigned short sY[2][128 * 40];
    __shared__ float sS1[128];
    __shared__ float sS2[128];
    const int tid = threadIdx.x;
    const int lane = tid & 63, w = tid >> 6;
    const int branch = blockIdx.y, b = blockIdx.z;
    const int t0 = blockIdx.x << 7;
    const int d = 1 << branch;
    const int coH = (w & 1) << 6, tH = (w >> 1) << 6;
    const int ml = lane & 15, kg = lane >> 4;

    if (tid < 128) { sS1[tid] = 0.f; sS2[tid] = 0.f; }

    f32x4 acc[4][4];
    #pragma unroll
    for (int mt = 0; mt < 4; mt++)
        #pragma unroll
        for (int nt = 0; nt < 4; nt++) acc[mt][nt] = (f32x4)(0.f);

    const unsigned short* WBb = WB + (size_t)branch * 49152;

    // staging index split: each thread handles li0 = tid and li1 = tid+256 (of 512 slots)
    const int wco0 = tid >> 2,        wkq0 = (tid & 3) << 3;
    const int wco1 = (tid + 256) >> 2, wkq1 = (tid & 3) << 3;
    // Y slots: n = li>>2, kq = (li&3)<<3  (same decomposition)

    // helper to load one Y slot for step kc
    auto loadY = [&](int li, int kc) -> u16x8 {
        const int tap = kc >> 2, hc = (kc & 3) << 5;
        const int goff = d * (tap - 1);
        int n = li >> 2, kq = (li & 3) << 3;
        int g = ((t0 + n) << 2) + goff;
        u16x8 v;
        if ((unsigned)g < 8192u) {
            v = *(const u16x8*)(yT + (((size_t)(b * 8192 + g)) << 7) + hc + kq);
        } else {
            #pragma unroll
            for (int e = 0; e < 8; e++) v[e] = 0;
        }
        return v;
    };
    auto loadW = [&](int co, int kq, int kc) -> u16x8 {
        return *(const u16x8*)(WBb + (size_t)co * 384 + (kc << 5) + kq);
    };

    // ---- prologue: stage kc=0 into buffer 0 ----
    {
        u16x8 vw0 = loadW(wco0, wkq0, 0);
        u16x8 vw1 = loadW(wco1, wkq1, 0);
        u16x8 vy0 = loadY(tid, 0);
        u16x8 vy1 = loadY(tid + 256, 0);
        *(u16x8*)&sW[0][wco0 * 40 + wkq0] = vw0;
        *(u16x8*)&sW[0][wco1 * 40 + wkq1] = vw1;
        *(u16x8*)&sY[0][(tid >> 2) * 40 + ((tid & 3) << 3)] = vy0;
        *(u16x8*)&sY[0][((tid + 256) >> 2) * 40 + ((tid & 3) << 3)] = vy1;
    }

    #pragma unroll 1
    for (int kc = 0; kc < 12; kc++) {
        const int cur = kc & 1;
        __syncthreads();   // buf[cur] staged; also protects buf[cur] from early overwrite

        // issue next-step global loads (latency hides under the MFMA cluster)
        u16x8 nw0, nw1, ny0, ny1;
        const bool more = (kc + 1 < 12);
        if (more) {
            nw0 = loadW(wco0, wkq0, kc + 1);
            nw1 = loadW(wco1, wkq1, kc + 1);
            ny0 = loadY(tid, kc + 1);
            ny1 = loadY(tid + 256, kc + 1);
        }

        // fragments + MFMA from buf[cur]
        s16x8 af[4], bfr[4];
        #pragma unroll
        for (int mt = 0; mt < 4; mt++)
            af[mt] = *(const s16x8*)&sW[cur][(coH + mt * 16 + ml) * 40 + (kg << 3)];
        #pragma unroll
        for (int nt = 0; nt < 4; nt++)
            bfr[nt] = *(const s16x8*)&sY[cur][(tH + nt * 16 + ml) * 40 + (kg << 3)];
        #pragma unroll
        for (int mt = 0; mt < 4; mt++)
            #pragma unroll
            for (int nt = 0; nt < 4; nt++)
                acc[mt][nt] = __builtin_amdgcn_mfma_f32_16x16x32_bf16(af[mt], bfr[nt], acc[mt][nt], 0, 0, 0);

        // write prefetched tile into the other buffer
        if (more) {
            *(u16x8*)&sW[cur ^ 1][wco0 * 40 + wkq0] = nw0;
            *(u16x8*)&sW[cur ^ 1][wco1 * 40 + wkq1] = nw1;
            *(u16x8*)&sY[cur ^ 1][(tid >> 2) * 40 + ((tid & 3) << 3)] = ny0;
            *(u16x8*)&sY[cur ^ 1][((tid + 256) >> 2) * 40 + ((tid & 3) << 3)] = ny1;
        }
    }

    const float* bp = (branch == 0) ? b1 : (branch == 1) ? b2 : (branch == 2) ? b3 : b4;
    #pragma unroll
    for (int mt = 0; mt < 4; mt++) {
        #pragma unroll
        for (int r = 0; r < 4; r++) {
            const int co = coH + mt * 16 + (kg << 2) + r;
            const float bb = bp[co];
            float ls1 = 0.f, ls2 = 0.f;
            #pragma unroll
            for (int nt = 0; nt < 4; nt++) {
                const int t = t0 + tH + nt * 16 + ml;
                float v = acc[mt][nt][r] + bb;
                if (branch != 0) v = (v >= 0.f) ? v : 0.3f * v;
                ls1 += v;
                ls2 = fmaf(v, v, ls2);
                z[(((size_t)((branch * 16 + b) * 128 + co)) << 11) + t] = f2bf(v);
            }
            // reduce the 16 t-lanes (ml) of this (co) within the wave
            #pragma unroll
            for (int o = 8; o > 0; o >>= 1) {
                ls1 += __shfl_down(ls1, o, 16);
                ls2 += __shfl_down(ls2, o, 16);
            }
            if (ml == 0) {
                atomicAdd(&sS1[co], ls1);
                atomicAdd(&sS2[co], ls2);
            }
        }
    }
    __syncthreads();
    if (tid < 128) {
        atomicAdd(&gstats[(((size_t)branch << 7) + tid) * 2],     sS1[tid]);
        atomicAdd(&gstats[(((size_t)branch << 7) + tid) * 2 + 1], sS2[tid]);
    }
}

// ============ kernel 5: BN affine apply (finalizes raw sums inline, fp32 out) ============
__global__ __launch_bounds__(256) void bn_apply(const unsigned short* __restrict__ z,
                                                const float* __restrict__ stats,
                                                const float* __restrict__ gam,
                                                const float* __restrict__ bet,
                                                float* __restrict__ out)
{
    const size_t idx = (((size_t)blockIdx.x << 8) + threadIdx.x) << 3;
    const int t = (int)(idx & 2047);
    const size_t bc = idx >> 11;
    const int ch = (int)(bc & 511);
    const int b = (int)(bc >> 9);
    const int branch = ch >> 7, co = ch & 127;
    const float s1 = stats[ch * 2], s2 = stats[ch * 2 + 1];
    const float m = s1 * (1.0f / 32768.0f);
    const float var = fmaf(-m, m, s2 * (1.0f / 32768.0f));
    const float inv = 1.0f / sqrtf(var + 1e-5f);
    const float ga = gam[co], be = bet[co];
    const float sc = ga * inv, sh = fmaf(-m, sc, be);
    const unsigned short* zp = z + (((size_t)((branch * 16 + b) * 128 + co)) << 11) + t;
    u16x8 v = *(const u16x8*)zp;
    float4 o0, o1;
    o0.x = fmaf(bf2f(v[0]), sc, sh); o0.y = fmaf(bf2f(v[1]), sc, sh);
    o0.z = fmaf(bf2f(v[2]), sc, sh); o0.w = fmaf(bf2f(v[3]), sc, sh);
    o1.x = fmaf(bf2f(v[4]), sc, sh); o1.y = fmaf(bf2f(v[5]), sc, sh);
    o1.z = fmaf(bf2f(v[6]), sc, sh); o1.w = fmaf(bf2f(v[7]), sc, sh);
    *(float4*)(out + idx)     = o0;
    *(float4*)(out + idx + 4) = o1;
}

extern "C" void kernel_launch(void* const* d_in, const int* in_sizes, int n_in,
                              void* d_out, int out_size, void* d_ws, size_t ws_size,
                              hipStream_t stream) {
    const float* x      = (const float*)d_in[0];
    const float* log_dt = (const float*)d_in[1];
    const float* A_log  = (const float*)d_in[2];
    const float* A_imag = (const float*)d_in[3];
    const float* B_re   = (const float*)d_in[4];
    const float* B_im   = (const float*)d_in[5];
    const float* C_re   = (const float*)d_in[6];
    const float* C_im   = (const float*)d_in[7];
    const float* Dp     = (const float*)d_in[8];
    const float* w1 = (const float*)d_in[9];
    const float* b1 = (const float*)d_in[10];
    const float* w2 = (const float*)d_in[11];
    const float* b2 = (const float*)d_in[12];
    const float* w3 = (const float*)d_in[13];
    const float* b3 = (const float*)d_in[14];
    const float* w4 = (const float*)d_in[15];
    const float* b4 = (const float*)d_in[16];
    const float* gam = (const float*)d_in[17];
    const float* bet = (const float*)d_in[18];

    float* w32p = (float*)d_ws;
    unsigned short* MATSp = (unsigned short*)((char*)d_ws + MATS_OFF);
    unsigned short* WBp = (unsigned short*)((char*)d_ws + WB_OFF);
    float* stats = (float*)((char*)d_ws + STAT_OFF);
    unsigned short* yws = (unsigned short*)((char*)d_ws + Y_OFF);
    unsigned short* yT  = (unsigned short*)((char*)d_ws + YT_OFF);
    unsigned short* zws = (unsigned short*)((char*)d_ws + Z_OFF);
    float* out = (float*)d_out;

    prep<<<dim3(896), dim3(256), 0, stream>>>(log_dt, A_log, A_imag, B_re, B_im, C_re, C_im,
                                              w32p, MATSp, w1, w2, w3, w4, WBp, stats);
    s4d_mfma<<<dim3(2048), dim3(256), 0, stream>>>(x, w32p, MATSp, Dp, yws);
    ytrans<<<dim3(128, 16), dim3(256), 0, stream>>>(yws, yT);
    conv_mfma<<<dim3(16, 4, 16), dim3(256), 0, stream>>>(yT, WBp, b1, b2, b3, b4, zws, stats);
    bn_apply<<<dim3(8192), dim3(256), 0, stream>>>(zws, stats, gam, bet, out);
}

// Round 15
// 262.310 us; speedup vs baseline: 1.3104x; 1.0079x over previous
//
#include <hip/hip_runtime.h>
#include <math.h>

typedef unsigned short u16x8 __attribute__((ext_vector_type(8)));
typedef unsigned short u16x2 __attribute__((ext_vector_type(2)));
typedef short s16x8 __attribute__((ext_vector_type(8)));
typedef float f32x4 __attribute__((ext_vector_type(4)));

__device__ __forceinline__ float bf2f(unsigned short u) {
    union { unsigned int i; float f; } v; v.i = ((unsigned int)u) << 16; return v.f;
}
__device__ __forceinline__ unsigned short f2bf(float f) {
    union { unsigned int i; float f; } v; v.f = f;
    unsigned int r = v.i + 0x7FFFu + ((v.i >> 16) & 1u);
    return (unsigned short)(r >> 16);
}

// ---------------- workspace layout (bytes) ----------------
#define MATS_OFF 16384
#define WB_OFF   548864
#define STAT_OFF 942080
#define Y_OFF    1048576
#define YT_OFF   34603008
#define Z_OFF    Y_OFF

// ============ kernel 1: merged prep — S4D matrix precompute (blocks 0..127),
// conv-weight bf16 pack (blocks 128..895), stats zero-init (block 128) ============
__global__ void prep(const float* __restrict__ log_dt,
                     const float* __restrict__ A_log,
                     const float* __restrict__ A_imag,
                     const float* __restrict__ B_re,
                     const float* __restrict__ B_im,
                     const float* __restrict__ C_re,
                     const float* __restrict__ C_im,
                     float* __restrict__ w32,
                     unsigned short* __restrict__ MATS,
                     const float* __restrict__ w1, const float* __restrict__ w2,
                     const float* __restrict__ w3, const float* __restrict__ w4,
                     unsigned short* __restrict__ WB,
                     float* __restrict__ stats)
{
    const int tid = threadIdx.x;
    if (blockIdx.x >= 128) {
        // ---- wpack path ----
        if (blockIdx.x == 128) {
            // zero the BN stats accumulator (512 ch x {s1,s2})
            ((float4*)stats)[tid] = make_float4(0.f, 0.f, 0.f, 0.f);
        }
        int idx = (blockIdx.x - 128) * 256 + tid;
        int br = idx / 49152;
        int r  = idx - br * 49152;
        int co = r / 384;
        int k  = r - co * 384;
        int tap = k >> 7, h = k & 127;
        const float* wp = (br == 0) ? w1 : (br == 1) ? w2 : (br == 2) ? w3 : w4;
        WB[idx] = f2bf(wp[co * 384 + h * 3 + tap]);
        return;
    }
    const int h = blockIdx.x;
    const double dt = exp((double)log_dt[h]);

    #pragma unroll 1
    for (int it = 0; it < 4; it++) {
        int idx = tid + (it << 8);
        int s = idx >> 5, i = idx & 31;
        int n = s >> 1;
        double Ar = -exp((double)A_log[h * 16 + n]);
        double Ai = (double)A_imag[h * 16 + n];
        double dr = dt * Ar, di = dt * Ai;
        double l = (double)(31 - i);
        double e = exp(l * dr);
        double val = (s & 1) ? e * sin(l * di) : e * cos(l * di);
        MATS[(size_t)h * 2080 + s * 32 + i] = f2bf((float)val);
    }
    #pragma unroll 1
    for (int it = 0; it < 4; it++) {
        int idx = tid + (it << 8);
        int j = idx >> 5, s = idx & 31;
        int n = s >> 1;
        double Ar = -exp((double)A_log[h * 16 + n]);
        double Ai = (double)A_imag[h * 16 + n];
        double dr = dt * Ar, di = dt * Ai;
        double ew = exp(dr);
        double wr = ew * cos(di), wi = ew * sin(di);
        double nr = wr - 1.0, ni = wi;
        double inv = 1.0 / (Ar * Ar + Ai * Ai);
        double tr = (nr * Ar + ni * Ai) * inv;
        double ti = (ni * Ar - nr * Ai) * inv;
        double Br = (double)B_re[h * 16 + n], Bi = (double)B_im[h * 16 + n];
        double dbr = tr * Br - ti * Bi, dbi = tr * Bi + ti * Br;
        double Cr = (double)C_re[h * 16 + n], Ci = (double)C_im[h * 16 + n];
        double cbr = Cr * dbr - Ci * dbi, cbi = Cr * dbi + Ci * dbr;
        double m = (double)(j + 1);
        double e = exp(m * dr);
        double pr = e * cos(m * di), pi = e * sin(m * di);
        double gr = cbr * pr - cbi * pi, gi = cbr * pi + cbi * pr;
        double val = (s & 1) ? -2.0 * gi : 2.0 * gr;
        MATS[(size_t)h * 2080 + 1024 + j * 32 + s] = f2bf((float)val);
    }
    {
        int l = tid >> 3, sub = tid & 7;
        double accd = 0.0;
        #pragma unroll 1
        for (int q = 0; q < 2; q++) {
            int n = sub * 2 + q;
            double Ar = -exp((double)A_log[h * 16 + n]);
            double Ai = (double)A_imag[h * 16 + n];
            double dr = dt * Ar, di = dt * Ai;
            double ew = exp(dr);
            double wr = ew * cos(di), wi = ew * sin(di);
            double nr = wr - 1.0, ni = wi;
            double inv = 1.0 / (Ar * Ar + Ai * Ai);
            double tr = (nr * Ar + ni * Ai) * inv;
            double ti = (ni * Ar - nr * Ai) * inv;
            double Br = (double)B_re[h * 16 + n], Bi = (double)B_im[h * 16 + n];
            double dbr = tr * Br - ti * Bi, dbi = tr * Bi + ti * Br;
            double Cr = (double)C_re[h * 16 + n], Ci = (double)C_im[h * 16 + n];
            double cbr = Cr * dbr - Ci * dbi, cbi = Cr * dbi + Ci * dbr;
            double l2 = (double)l;
            double e = exp(l2 * dr);
            double wlr = e * cos(l2 * di), wli = e * sin(l2 * di);
            accd += cbr * wlr - cbi * wli;
        }
        float accf = (float)(2.0 * accd);
        #pragma unroll
        for (int o = 4; o > 0; o >>= 1) accf += __shfl_down(accf, o, 8);
        if (sub == 0) MATS[(size_t)h * 2080 + 2048 + l] = f2bf(accf);
    }
    if (tid < 16) {
        int n = tid;
        double Ar = -exp((double)A_log[h * 16 + n]);
        double Ai = (double)A_imag[h * 16 + n];
        double dr = dt * Ar, di = dt * Ai;
        double e = exp(32.0 * dr);
        w32[h * 32 + 2 * n]     = (float)(e * cos(32.0 * di));
        w32[h * 32 + 2 * n + 1] = (float)(e * sin(32.0 * di));
    }
}

// ============ kernel 2: S4D — MFMA chunk matmuls + shuffle carry scan ============
// s4d is VALU+latency bound (VALUBusy 34%, occupancy pinned ~19.5%). The 16
// per-thread 6-step power ladders (~770 ops) are replaced by block-shared
// ptab[n][lane] = w32^lane built once (4 entries/thread, bit-identical mult
// order); scan wrapped in s_setprio(1)/(0) (T5).
__global__ __launch_bounds__(256, 2) void s4d_mfma(const float* __restrict__ x,
                                                   const float* __restrict__ w32,
                                                   const unsigned short* __restrict__ MATS,
                                                   const float* __restrict__ Dp,
                                                   unsigned short* __restrict__ yout)
{
    __shared__ unsigned short sXc[256 * 40];
    __shared__ unsigned short sM[3840];        // V @0, TK @1280, G @2560 (stride 40)
    __shared__ float spow2[256];               // w32^(2^k), k=0..7
    __shared__ float ptab[2048];               // [n][lane]: w32^lane, float2 (8 KB)
    __shared__ unsigned short skr[32];
    __shared__ float swc[128];                 // cross-wave carries 4x32
    __shared__ float scratch[5120];            // 16 x 260 unpack buffer / sCc u16 (20.5 KB)
    const int tid = threadIdx.x;
    const int bh = blockIdx.x;
    const int h = bh & 127;
    const int lane = tid & 63, w = tid >> 6;
    const int ml = lane & 15, kg = lane >> 4;

    float xr[32];
    const float4* xp4 = (const float4*)(x + ((size_t)bh << 13) + (tid << 5));
    #pragma unroll
    for (int i = 0; i < 8; i++) {
        float4 v = xp4[i];
        xr[4 * i] = v.x; xr[4 * i + 1] = v.y; xr[4 * i + 2] = v.z; xr[4 * i + 3] = v.w;
    }
    #pragma unroll
    for (int g = 0; g < 4; g++) {
        u16x8 pk;
        #pragma unroll
        for (int e = 0; e < 8; e++) pk[e] = f2bf(xr[g * 8 + e]);
        *(u16x8*)&sXc[tid * 40 + g * 8] = pk;
    }
    {
        int matv = tid >> 7, r = (tid >> 2) & 31, sg = tid & 3;
        u16x8 v = *(const u16x8*)(MATS + (size_t)h * 2080 + matv * 1024 + r * 32 + sg * 8);
        *(u16x8*)&sM[matv * 2560 + r * 40 + sg * 8] = v;
    }
    if (tid < 4) {
        u16x8 v = *(const u16x8*)(MATS + (size_t)h * 2080 + 2048 + tid * 8);
        *(u16x8*)&skr[tid * 8] = v;
    }
    if (tid < 16) {
        float rr = w32[h * 32 + 2 * tid], ii = w32[h * 32 + 2 * tid + 1];
        #pragma unroll
        for (int k = 0; k < 8; k++) {
            spow2[k * 32 + 2 * tid] = rr; spow2[k * 32 + 2 * tid + 1] = ii;
            float n2r = rr * rr - ii * ii, n2i = 2.f * rr * ii;
            rr = n2r; ii = n2i;
        }
    }
    __syncthreads();
    #pragma unroll
    for (int it = 0; it < 4; it++) {
        int idx = tid + (it << 8);
        int j = idx >> 5, i = idx & 31;
        sM[1280 + j * 40 + i] = (i <= j) ? skr[j - i] : (unsigned short)0;
    }
    // build ptab[n][j] = w32(h,n)^j, j=0..63 (4 entries/thread, same mult order as
    // the old per-thread ladder -> bit-identical values)
    #pragma unroll
    for (int q2 = 0; q2 < 4; q2++) {
        int idx = (tid << 2) + q2;          // 0..1023
        int j = idx >> 4, n = idx & 15;
        float prr = 1.f, pii = 0.f;
        #pragma unroll
        for (int k = 0; k < 6; k++) {
            const bool bit = (j >> k) & 1;
            float mr = spow2[(k << 5) + 2 * n], mi = spow2[(k << 5) + 2 * n + 1];
            float nr2 = prr * mr - pii * mi;
            float ni2 = fmaf(prr, mi, pii * mr);
            prr = bit ? nr2 : prr;
            pii = bit ? ni2 : pii;
        }
        ptab[n * 128 + j * 2]     = prr;
        ptab[n * 128 + j * 2 + 1] = pii;
    }
    __syncthreads();

    // ---- E = V @ Xc ----
    f32x4 acc[2][4];
    #pragma unroll
    for (int mt = 0; mt < 2; mt++)
        #pragma unroll
        for (int nt = 0; nt < 4; nt++) acc[mt][nt] = (f32x4)(0.f);
    {
        s16x8 af[2], bfr[4];
        #pragma unroll
        for (int mt = 0; mt < 2; mt++)
            af[mt] = *(const s16x8*)&sM[(mt * 16 + ml) * 40 + kg * 8];
        #pragma unroll
        for (int nt = 0; nt < 4; nt++)
            bfr[nt] = *(const s16x8*)&sXc[(w * 64 + nt * 16 + ml) * 40 + kg * 8];
        #pragma unroll
        for (int mt = 0; mt < 2; mt++)
            #pragma unroll
            for (int nt = 0; nt < 4; nt++)
                acc[mt][nt] = __builtin_amdgcn_mfma_f32_16x16x32_bf16(af[mt], bfr[nt], acc[mt][nt], 0, 0, 0);
    }
    // ---- unpack E fragments -> per-thread zr/zi, two explicit 16-row passes ----
    float zr[16], zi[16];
    // pass 0: acc[0] rows 0..15
    #pragma unroll
    for (int nt = 0; nt < 4; nt++)
        #pragma unroll
        for (int r = 0; r < 4; r++)
            scratch[(kg * 4 + r) * 260 + (w * 64 + nt * 16 + ml)] = acc[0][nt][r];
    __syncthreads();
    #pragma unroll
    for (int q = 0; q < 8; q++) {
        zr[q] = scratch[(2 * q) * 260 + tid];
        zi[q] = scratch[(2 * q + 1) * 260 + tid];
    }
    __syncthreads();
    // pass 1: acc[1] rows 16..31
    #pragma unroll
    for (int nt = 0; nt < 4; nt++)
        #pragma unroll
        for (int r = 0; r < 4; r++)
            scratch[(kg * 4 + r) * 260 + (w * 64 + nt * 16 + ml)] = acc[1][nt][r];
    __syncthreads();
    #pragma unroll
    for (int q = 0; q < 8; q++) {
        zr[8 + q] = scratch[(2 * q) * 260 + tid];
        zi[8 + q] = scratch[(2 * q + 1) * 260 + tid];
    }

    // ---- in-wave inclusive scan (shuffles) ----
    __builtin_amdgcn_s_setprio(1);
    #pragma unroll 1
    for (int k = 0; k < 6; k++) {
        const int o = 1 << k;
        const bool act = lane >= o;
        #pragma unroll
        for (int n = 0; n < 16; n++) {
            float lr = __shfl(zr[n], lane - o);
            float li = __shfl(zi[n], lane - o);
            float mr = spow2[(k << 5) + 2 * n], mi = spow2[(k << 5) + 2 * n + 1];
            float nzr = fmaf(mr, lr, fmaf(-mi, li, zr[n]));
            float nzi = fmaf(mr, li, fmaf(mi, lr, zi[n]));
            zr[n] = act ? nzr : zr[n];
            zi[n] = act ? nzi : zi[n];
        }
    }
    if (lane == 63) {
        #pragma unroll
        for (int n = 0; n < 16; n++) {
            swc[w * 32 + 2 * n]     = zr[n];
            swc[w * 32 + 2 * n + 1] = zi[n];
        }
    }
    __syncthreads();
    float qr[16], qi[16];
    #pragma unroll
    for (int n = 0; n < 16; n++) { qr[n] = 0.f; qi[n] = 0.f; }
    #pragma unroll 1
    for (int a = 0; a < 3; a++) {
        if (a < w) {
            int p = w - 1 - a;
            #pragma unroll
            for (int n = 0; n < 16; n++) {
                float ar = swc[a * 32 + 2 * n], ai = swc[a * 32 + 2 * n + 1];
                float mr = 1.f, mi = 0.f;
                if (p > 0) { mr = spow2[((5 + p) << 5) + 2 * n]; mi = spow2[((5 + p) << 5) + 2 * n + 1]; }
                qr[n] = fmaf(mr, ar, fmaf(-mi, ai, qr[n]));
                qi[n] = fmaf(mr, ai, fmaf(mi, ar, qi[n]));
            }
        }
    }
    // final update: w32^lane from the block-shared table
    #pragma unroll
    for (int n = 0; n < 16; n++) {
        float2 pj = *(const float2*)&ptab[n * 128 + (lane << 1)];
        float pr = __shfl(zr[n], lane - 1);
        float pi = __shfl(zi[n], lane - 1);
        pr = (lane == 0) ? 0.f : pr;
        pi = (lane == 0) ? 0.f : pi;
        zr[n] = fmaf(pj.x, qr[n], fmaf(-pj.y, qi[n], pr));
        zi[n] = fmaf(pj.x, qi[n], fmaf(pj.y, qr[n], pi));
    }
    __builtin_amdgcn_s_setprio(0);
    {
        unsigned short* sCc = (unsigned short*)scratch;
        #pragma unroll
        for (int g = 0; g < 4; g++) {
            u16x8 pk;
            #pragma unroll
            for (int q = 0; q < 4; q++) {
                pk[2 * q]     = f2bf(zr[g * 4 + q]);
                pk[2 * q + 1] = f2bf(zi[g * 4 + q]);
            }
            *(u16x8*)&sCc[tid * 40 + g * 8] = pk;
        }
    }
    __syncthreads();

    // ---- y = TK @ Xc + G @ Cc ----
    #pragma unroll
    for (int mt = 0; mt < 2; mt++)
        #pragma unroll
        for (int nt = 0; nt < 4; nt++) acc[mt][nt] = (f32x4)(0.f);
    {
        const unsigned short* sCc = (const unsigned short*)scratch;
        s16x8 a1[2], a2[2], bfx[4], bfc[4];
        #pragma unroll
        for (int mt = 0; mt < 2; mt++) {
            a1[mt] = *(const s16x8*)&sM[1280 + (mt * 16 + ml) * 40 + kg * 8];
            a2[mt] = *(const s16x8*)&sM[2560 + (mt * 16 + ml) * 40 + kg * 8];
        }
        #pragma unroll
        for (int nt = 0; nt < 4; nt++) {
            bfx[nt] = *(const s16x8*)&sXc[(w * 64 + nt * 16 + ml) * 40 + kg * 8];
            bfc[nt] = *(const s16x8*)&sCc[(w * 64 + nt * 16 + ml) * 40 + kg * 8];
        }
        #pragma unroll
        for (int mt = 0; mt < 2; mt++)
            #pragma unroll
            for (int nt = 0; nt < 4; nt++) {
                acc[mt][nt] = __builtin_amdgcn_mfma_f32_16x16x32_bf16(a1[mt], bfx[nt], acc[mt][nt], 0, 0, 0);
                acc[mt][nt] = __builtin_amdgcn_mfma_f32_16x16x32_bf16(a2[mt], bfc[nt], acc[mt][nt], 0, 0, 0);
            }
    }
    // ---- output transpose + D-residual, two explicit 16-row passes (static idx) ----
    const float Dh = Dp[h];
    u16x8* yp = (u16x8*)(yout + ((size_t)bh << 13) + (tid << 5));
    // pass 0: acc[0] -> y rows 0..15 (output groups g=0,1)
    __syncthreads();   // sCc MFMA reads done before overwrite
    #pragma unroll
    for (int nt = 0; nt < 4; nt++)
        #pragma unroll
        for (int r = 0; r < 4; r++)
            scratch[(kg * 4 + r) * 260 + (w * 64 + nt * 16 + ml)] = acc[0][nt][r];
    __syncthreads();
    #pragma unroll
    for (int g = 0; g < 2; g++) {
        u16x8 pk;
        #pragma unroll
        for (int e = 0; e < 8; e++) {
            int i = g * 8 + e;
            pk[e] = f2bf(fmaf(Dh, xr[i], scratch[i * 260 + tid]));
        }
        yp[g] = pk;
    }
    // pass 1: acc[1] -> y rows 16..31 (output groups g=2,3)
    __syncthreads();
    #pragma unroll
    for (int nt = 0; nt < 4; nt++)
        #pragma unroll
        for (int r = 0; r < 4; r++)
            scratch[(kg * 4 + r) * 260 + (w * 64 + nt * 16 + ml)] = acc[1][nt][r];
    __syncthreads();
    #pragma unroll
    for (int g = 2; g < 4; g++) {
        u16x8 pk;
        #pragma unroll
        for (int e = 0; e < 8; e++) {
            int i = g * 8 + e;
            pk[e] = f2bf(fmaf(Dh, xr[i], scratch[(i - 16) * 260 + tid]));
        }
        yp[g] = pk;
    }
}

// ============ kernel 3: transpose y[bh][g] -> yT[b][g][h] ============
__global__ __launch_bounds__(256) void ytrans(const unsigned short* __restrict__ y,
                                              unsigned short* __restrict__ yT)
{
    __shared__ unsigned short sT[128 * 72];
    const int b = blockIdx.y, g0 = blockIdx.x << 6;
    const int tid = threadIdx.x;
    #pragma unroll
    for (int j = 0; j < 4; j++) {
        int li = tid + (j << 8);
        int h = li >> 3, g8 = (li & 7) << 3;
        u16x8 v = *(const u16x8*)(y + (((size_t)(b * 128 + h)) << 13) + g0 + g8);
        int gp = (g8 + (((h >> 3) & 7) << 3)) & 63;
        *(u16x8*)&sT[h * 72 + gp] = v;
    }
    __syncthreads();
    #pragma unroll
    for (int j = 0; j < 4; j++) {
        int li = tid + (j << 8);
        int g = li >> 4, h8 = (li & 15) << 3;
        u16x8 o;
        #pragma unroll
        for (int e = 0; e < 8; e++) {
            int h = h8 + e;
            int gp = (g + (((h >> 3) & 7) << 3)) & 63;
            o[e] = sT[h * 72 + gp];
        }
        *(u16x8*)(yT + (((size_t)(b * 8192 + g0 + g)) << 7) + h8) = o;
    }
}

// ============ kernel 4: MFMA dilated conv + bias + LeakyReLU + fused BN stats ============
__global__ __launch_bounds__(256) void conv_mfma(
    const unsigned short* __restrict__ yT,
    const unsigned short* __restrict__ WB,
    const float* __restrict__ b1, const float* __restrict__ b2,
    const float* __restrict__ b3, const float* __restrict__ b4,
    unsigned short* __restrict__ z,
    float* __restrict__ gstats)
{
    __shared__ unsigned short sW[2][128 * 40];
    __shared__ unsigned short sY[2][128 * 40];
    __shared__ float sS1[128];
    __shared__ float sS2[128];
    const int tid = threadIdx.x;
    const int lane = tid & 63, w = tid >> 6;
    const int branch = blockIdx.y, b = blockIdx.z;
    const int t0 = blockIdx.x << 7;
    const int d = 1 << branch;
    const int coH = (w & 1) << 6, tH = (w >> 1) << 6;
    const int ml = lane & 15, kg = lane >> 4;

    if (tid < 128) { sS1[tid] = 0.f; sS2[tid] = 0.f; }

    f32x4 acc[4][4];
    #pragma unroll
    for (int mt = 0; mt < 4; mt++)
        #pragma unroll
        for (int nt = 0; nt < 4; nt++) acc[mt][nt] = (f32x4)(0.f);

    const unsigned short* WBb = WB + (size_t)branch * 49152;

    const int wco0 = tid >> 2,        wkq0 = (tid & 3) << 3;
    const int wco1 = (tid + 256) >> 2, wkq1 = (tid & 3) << 3;

    auto loadY = [&](int li, int kc) -> u16x8 {
        const int tap = kc >> 2, hc = (kc & 3) << 5;
        const int goff = d * (tap - 1);
        int n = li >> 2, kq = (li & 3) << 3;
        int g = ((t0 + n) << 2) + goff;
        u16x8 v;
        if ((unsigned)g < 8192u) {
            v = *(const u16x8*)(yT + (((size_t)(b * 8192 + g)) << 7) + hc + kq);
        } else {
            #pragma unroll
            for (int e = 0; e < 8; e++) v[e] = 0;
        }
        return v;
    };
    auto loadW = [&](int co, int kq, int kc) -> u16x8 {
        return *(const u16x8*)(WBb + (size_t)co * 384 + (kc << 5) + kq);
    };

    // ---- prologue: stage kc=0 into buffer 0 ----
    {
        u16x8 vw0 = loadW(wco0, wkq0, 0);
        u16x8 vw1 = loadW(wco1, wkq1, 0);
        u16x8 vy0 = loadY(tid, 0);
        u16x8 vy1 = loadY(tid + 256, 0);
        *(u16x8*)&sW[0][wco0 * 40 + wkq0] = vw0;
        *(u16x8*)&sW[0][wco1 * 40 + wkq1] = vw1;
        *(u16x8*)&sY[0][(tid >> 2) * 40 + ((tid & 3) << 3)] = vy0;
        *(u16x8*)&sY[0][((tid + 256) >> 2) * 40 + ((tid & 3) << 3)] = vy1;
    }

    #pragma unroll 1
    for (int kc = 0; kc < 12; kc++) {
        const int cur = kc & 1;
        __syncthreads();

        u16x8 nw0, nw1, ny0, ny1;
        const bool more = (kc + 1 < 12);
        if (more) {
            nw0 = loadW(wco0, wkq0, kc + 1);
            nw1 = loadW(wco1, wkq1, kc + 1);
            ny0 = loadY(tid, kc + 1);
            ny1 = loadY(tid + 256, kc + 1);
        }

        s16x8 af[4], bfr[4];
        #pragma unroll
        for (int mt = 0; mt < 4; mt++)
            af[mt] = *(const s16x8*)&sW[cur][(coH + mt * 16 + ml) * 40 + (kg << 3)];
        #pragma unroll
        for (int nt = 0; nt < 4; nt++)
            bfr[nt] = *(const s16x8*)&sY[cur][(tH + nt * 16 + ml) * 40 + (kg << 3)];
        #pragma unroll
        for (int mt = 0; mt < 4; mt++)
            #pragma unroll
            for (int nt = 0; nt < 4; nt++)
                acc[mt][nt] = __builtin_amdgcn_mfma_f32_16x16x32_bf16(af[mt], bfr[nt], acc[mt][nt], 0, 0, 0);

        if (more) {
            *(u16x8*)&sW[cur ^ 1][wco0 * 40 + wkq0] = nw0;
            *(u16x8*)&sW[cur ^ 1][wco1 * 40 + wkq1] = nw1;
            *(u16x8*)&sY[cur ^ 1][(tid >> 2) * 40 + ((tid & 3) << 3)] = ny0;
            *(u16x8*)&sY[cur ^ 1][((tid + 256) >> 2) * 40 + ((tid & 3) << 3)] = ny1;
        }
    }

    const float* bp = (branch == 0) ? b1 : (branch == 1) ? b2 : (branch == 2) ? b3 : b4;
    #pragma unroll
    for (int mt = 0; mt < 4; mt++) {
        #pragma unroll
        for (int r = 0; r < 4; r++) {
            const int co = coH + mt * 16 + (kg << 2) + r;
            const float bb = bp[co];
            float ls1 = 0.f, ls2 = 0.f;
            #pragma unroll
            for (int nt = 0; nt < 4; nt++) {
                const int t = t0 + tH + nt * 16 + ml;
                float v = acc[mt][nt][r] + bb;
                if (branch != 0) v = (v >= 0.f) ? v : 0.3f * v;
                ls1 += v;
                ls2 = fmaf(v, v, ls2);
                z[(((size_t)((branch * 16 + b) * 128 + co)) << 11) + t] = f2bf(v);
            }
            #pragma unroll
            for (int o = 8; o > 0; o >>= 1) {
                ls1 += __shfl_down(ls1, o, 16);
                ls2 += __shfl_down(ls2, o, 16);
            }
            if (ml == 0) {
                atomicAdd(&sS1[co], ls1);
                atomicAdd(&sS2[co], ls2);
            }
        }
    }
    __syncthreads();
    if (tid < 128) {
        atomicAdd(&gstats[(((size_t)branch << 7) + tid) * 2],     sS1[tid]);
        atomicAdd(&gstats[(((size_t)branch << 7) + tid) * 2 + 1], sS2[tid]);
    }
}

// ============ kernel 5: BN affine apply (finalizes raw sums inline, fp32 out) ============
__global__ __launch_bounds__(256) void bn_apply(const unsigned short* __restrict__ z,
                                                const float* __restrict__ stats,
                                                const float* __restrict__ gam,
                                                const float* __restrict__ bet,
                                                float* __restrict__ out)
{
    const size_t idx = (((size_t)blockIdx.x << 8) + threadIdx.x) << 3;
    const int t = (int)(idx & 2047);
    const size_t bc = idx >> 11;
    const int ch = (int)(bc & 511);
    const int b = (int)(bc >> 9);
    const int branch = ch >> 7, co = ch & 127;
    const float s1 = stats[ch * 2], s2 = stats[ch * 2 + 1];
    const float m = s1 * (1.0f / 32768.0f);
    const float var = fmaf(-m, m, s2 * (1.0f / 32768.0f));
    const float inv = 1.0f / sqrtf(var + 1e-5f);
    const float ga = gam[co], be = bet[co];
    const float sc = ga * inv, sh = fmaf(-m, sc, be);
    const unsigned short* zp = z + (((size_t)((branch * 16 + b) * 128 + co)) << 11) + t;
    u16x8 v = *(const u16x8*)zp;
    float4 o0, o1;
    o0.x = fmaf(bf2f(v[0]), sc, sh); o0.y = fmaf(bf2f(v[1]), sc, sh);
    o0.z = fmaf(bf2f(v[2]), sc, sh); o0.w = fmaf(bf2f(v[3]), sc, sh);
    o1.x = fmaf(bf2f(v[4]), sc, sh); o1.y = fmaf(bf2f(v[5]), sc, sh);
    o1.z = fmaf(bf2f(v[6]), sc, sh); o1.w = fmaf(bf2f(v[7]), sc, sh);
    *(float4*)(out + idx)     = o0;
    *(float4*)(out + idx + 4) = o1;
}

extern "C" void kernel_launch(void* const* d_in, const int* in_sizes, int n_in,
                              void* d_out, int out_size, void* d_ws, size_t ws_size,
                              hipStream_t stream) {
    const float* x      = (const float*)d_in[0];
    const float* log_dt = (const float*)d_in[1];
    const float* A_log  = (const float*)d_in[2];
    const float* A_imag = (const float*)d_in[3];
    const float* B_re   = (const float*)d_in[4];
    const float* B_im   = (const float*)d_in[5];
    const float* C_re   = (const float*)d_in[6];
    const float* C_im   = (const float*)d_in[7];
    const float* Dp     = (const float*)d_in[8];
    const float* w1 = (const float*)d_in[9];
    const float* b1 = (const float*)d_in[10];
    const float* w2 = (const float*)d_in[11];
    const float* b2 = (const float*)d_in[12];
    const float* w3 = (const float*)d_in[13];
    const float* b3 = (const float*)d_in[14];
    const float* w4 = (const float*)d_in[15];
    const float* b4 = (const float*)d_in[16];
    const float* gam = (const float*)d_in[17];
    const float* bet = (const float*)d_in[18];

    float* w32p = (float*)d_ws;
    unsigned short* MATSp = (unsigned short*)((char*)d_ws + MATS_OFF);
    unsigned short* WBp = (unsigned short*)((char*)d_ws + WB_OFF);
    float* stats = (float*)((char*)d_ws + STAT_OFF);
    unsigned short* yws = (unsigned short*)((char*)d_ws + Y_OFF);
    unsigned short* yT  = (unsigned short*)((char*)d_ws + YT_OFF);
    unsigned short* zws = (unsigned short*)((char*)d_ws + Z_OFF);
    float* out = (float*)d_out;

    prep<<<dim3(896), dim3(256), 0, stream>>>(log_dt, A_log, A_imag, B_re, B_im, C_re, C_im,
                                              w32p, MATSp, w1, w2, w3, w4, WBp, stats);
    s4d_mfma<<<dim3(2048), dim3(256), 0, stream>>>(x, w32p, MATSp, Dp, yws);
    ytrans<<<dim3(128, 16), dim3(256), 0, stream>>>(yws, yT);
    conv_mfma<<<dim3(16, 4, 16), dim3(256), 0, stream>>>(yT, WBp, b1, b2, b3, b4, zws, stats);
    bn_apply<<<dim3(8192), dim3(256), 0, stream>>>(zws, stats, gam, bet, out);
}

// Round 20
// 260.063 us; speedup vs baseline: 1.3217x; 1.0086x over previous
//
#include <hip/hip_runtime.h>
#include <math.h>

typedef unsigned short u16x8 __attribute__((ext_vector_type(8)));
typedef unsigned short u16x2 __attribute__((ext_vector_type(2)));
typedef short s16x8 __attribute__((ext_vector_type(8)));
typedef float f32x4 __attribute__((ext_vector_type(4)));

__device__ __forceinline__ float bf2f(unsigned short u) {
    union { unsigned int i; float f; } v; v.i = ((unsigned int)u) << 16; return v.f;
}
__device__ __forceinline__ unsigned short f2bf(float f) {
    union { unsigned int i; float f; } v; v.f = f;
    unsigned int r = v.i + 0x7FFFu + ((v.i >> 16) & 1u);
    return (unsigned short)(r >> 16);
}

// ---------------- workspace layout (bytes) ----------------
#define MATS_OFF 16384
#define WB_OFF   548864
#define STAT_OFF 942080
#define Y_OFF    1048576
#define YT_OFF   34603008
#define Z_OFF    Y_OFF

// ============ kernel 1: merged prep — S4D matrix precompute (blocks 0..127),
// conv-weight bf16 pack (blocks 128..895), stats zero-init (block 128).
// Per-n f64 chain (Ar/Ai/dr/di + CB complex chain) hoisted to LDS — computed
// once by 16 threads with identical formulas/order (bit-identical values).
__global__ void prep(const float* __restrict__ log_dt,
                     const float* __restrict__ A_log,
                     const float* __restrict__ A_imag,
                     const float* __restrict__ B_re,
                     const float* __restrict__ B_im,
                     const float* __restrict__ C_re,
                     const float* __restrict__ C_im,
                     float* __restrict__ w32,
                     unsigned short* __restrict__ MATS,
                     const float* __restrict__ w1, const float* __restrict__ w2,
                     const float* __restrict__ w3, const float* __restrict__ w4,
                     unsigned short* __restrict__ WB,
                     float* __restrict__ stats)
{
    __shared__ double sdr[16], sdi[16], scbr[16], scbi[16];
    const int tid = threadIdx.x;
    if (blockIdx.x >= 128) {
        // ---- wpack path ----
        if (blockIdx.x == 128) {
            // zero the BN stats accumulator (512 ch x {s1,s2})
            ((float4*)stats)[tid] = make_float4(0.f, 0.f, 0.f, 0.f);
        }
        int idx = (blockIdx.x - 128) * 256 + tid;
        int br = idx / 49152;
        int r  = idx - br * 49152;
        int co = r / 384;
        int k  = r - co * 384;
        int tap = k >> 7, h = k & 127;
        const float* wp = (br == 0) ? w1 : (br == 1) ? w2 : (br == 2) ? w3 : w4;
        WB[idx] = f2bf(wp[co * 384 + h * 3 + tap]);
        return;
    }
    const int h = blockIdx.x;
    const double dt = exp((double)log_dt[h]);

    // ---- per-n chain, computed once (same formulas/order as the old
    // per-element recompute -> bit-identical) ----
    if (tid < 16) {
        int n = tid;
        double Ar = -exp((double)A_log[h * 16 + n]);
        double Ai = (double)A_imag[h * 16 + n];
        double dr = dt * Ar, di = dt * Ai;
        double ew = exp(dr);
        double wr = ew * cos(di), wi = ew * sin(di);
        double nr = wr - 1.0, ni = wi;
        double inv = 1.0 / (Ar * Ar + Ai * Ai);
        double tr = (nr * Ar + ni * Ai) * inv;
        double ti = (ni * Ar - nr * Ai) * inv;
        double Br = (double)B_re[h * 16 + n], Bi = (double)B_im[h * 16 + n];
        double dbr = tr * Br - ti * Bi, dbi = tr * Bi + ti * Br;
        double Cr = (double)C_re[h * 16 + n], Ci = (double)C_im[h * 16 + n];
        scbr[n] = Cr * dbr - Ci * dbi;
        scbi[n] = Cr * dbi + Ci * dbr;
        sdr[n] = dr;
        sdi[n] = di;
        // w32 output (identical formula as before, just moved here)
        double e32 = exp(32.0 * dr);
        w32[h * 32 + 2 * n]     = (float)(e32 * cos(32.0 * di));
        w32[h * 32 + 2 * n + 1] = (float)(e32 * sin(32.0 * di));
    }
    __syncthreads();

    // ---- V matrix ----
    #pragma unroll 1
    for (int it = 0; it < 4; it++) {
        int idx = tid + (it << 8);
        int s = idx >> 5, i = idx & 31;
        int n = s >> 1;
        double dr = sdr[n], di = sdi[n];
        double l = (double)(31 - i);
        double e = exp(l * dr);
        double val = (s & 1) ? e * sin(l * di) : e * cos(l * di);
        MATS[(size_t)h * 2080 + s * 32 + i] = f2bf((float)val);
    }
    // ---- G matrix ----
    #pragma unroll 1
    for (int it = 0; it < 4; it++) {
        int idx = tid + (it << 8);
        int j = idx >> 5, s = idx & 31;
        int n = s >> 1;
        double dr = sdr[n], di = sdi[n];
        double cbr = scbr[n], cbi = scbi[n];
        double m = (double)(j + 1);
        double e = exp(m * dr);
        double pr = e * cos(m * di), pi = e * sin(m * di);
        double gr = cbr * pr - cbi * pi, gi = cbr * pi + cbi * pr;
        double val = (s & 1) ? -2.0 * gi : 2.0 * gr;
        MATS[(size_t)h * 2080 + 1024 + j * 32 + s] = f2bf((float)val);
    }
    // ---- kernel-row (kr) reduction ----
    {
        int l = tid >> 3, sub = tid & 7;
        double accd = 0.0;
        #pragma unroll 1
        for (int q = 0; q < 2; q++) {
            int n = sub * 2 + q;
            double l2 = (double)l;
            double e = exp(l2 * sdr[n]);
            double wlr = e * cos(l2 * sdi[n]), wli = e * sin(l2 * sdi[n]);
            accd += scbr[n] * wlr - scbi[n] * wli;
        }
        float accf = (float)(2.0 * accd);
        #pragma unroll
        for (int o = 4; o > 0; o >>= 1) accf += __shfl_down(accf, o, 8);
        if (sub == 0) MATS[(size_t)h * 2080 + 2048 + l] = f2bf(accf);
    }
}

// ============ kernel 2: S4D — MFMA chunk matmuls + shuffle carry scan ============
// (measured 262.3 us pipeline config: ptab + setprio; byte-identical to round 15)
__global__ __launch_bounds__(256, 2) void s4d_mfma(const float* __restrict__ x,
                                                   const float* __restrict__ w32,
                                                   const unsigned short* __restrict__ MATS,
                                                   const float* __restrict__ Dp,
                                                   unsigned short* __restrict__ yout)
{
    __shared__ unsigned short sXc[256 * 40];
    __shared__ unsigned short sM[3840];        // V @0, TK @1280, G @2560 (stride 40)
    __shared__ float spow2[256];               // w32^(2^k), k=0..7
    __shared__ float ptab[2048];               // [n][lane]: w32^lane, float2 (8 KB)
    __shared__ unsigned short skr[32];
    __shared__ float swc[128];                 // cross-wave carries 4x32
    __shared__ float scratch[5120];            // 16 x 260 unpack buffer / sCc u16 (20.5 KB)
    const int tid = threadIdx.x;
    const int bh = blockIdx.x;
    const int h = bh & 127;
    const int lane = tid & 63, w = tid >> 6;
    const int ml = lane & 15, kg = lane >> 4;

    float xr[32];
    const float4* xp4 = (const float4*)(x + ((size_t)bh << 13) + (tid << 5));
    #pragma unroll
    for (int i = 0; i < 8; i++) {
        float4 v = xp4[i];
        xr[4 * i] = v.x; xr[4 * i + 1] = v.y; xr[4 * i + 2] = v.z; xr[4 * i + 3] = v.w;
    }
    #pragma unroll
    for (int g = 0; g < 4; g++) {
        u16x8 pk;
        #pragma unroll
        for (int e = 0; e < 8; e++) pk[e] = f2bf(xr[g * 8 + e]);
        *(u16x8*)&sXc[tid * 40 + g * 8] = pk;
    }
    {
        int matv = tid >> 7, r = (tid >> 2) & 31, sg = tid & 3;
        u16x8 v = *(const u16x8*)(MATS + (size_t)h * 2080 + matv * 1024 + r * 32 + sg * 8);
        *(u16x8*)&sM[matv * 2560 + r * 40 + sg * 8] = v;
    }
    if (tid < 4) {
        u16x8 v = *(const u16x8*)(MATS + (size_t)h * 2080 + 2048 + tid * 8);
        *(u16x8*)&skr[tid * 8] = v;
    }
    if (tid < 16) {
        float rr = w32[h * 32 + 2 * tid], ii = w32[h * 32 + 2 * tid + 1];
        #pragma unroll
        for (int k = 0; k < 8; k++) {
            spow2[k * 32 + 2 * tid] = rr; spow2[k * 32 + 2 * tid + 1] = ii;
            float n2r = rr * rr - ii * ii, n2i = 2.f * rr * ii;
            rr = n2r; ii = n2i;
        }
    }
    __syncthreads();
    #pragma unroll
    for (int it = 0; it < 4; it++) {
        int idx = tid + (it << 8);
        int j = idx >> 5, i = idx & 31;
        sM[1280 + j * 40 + i] = (i <= j) ? skr[j - i] : (unsigned short)0;
    }
    // build ptab[n][j] = w32(h,n)^j, j=0..63 (4 entries/thread, same mult order as
    // the old per-thread ladder -> bit-identical values)
    #pragma unroll
    for (int q2 = 0; q2 < 4; q2++) {
        int idx = (tid << 2) + q2;          // 0..1023
        int j = idx >> 4, n = idx & 15;
        float prr = 1.f, pii = 0.f;
        #pragma unroll
        for (int k = 0; k < 6; k++) {
            const bool bit = (j >> k) & 1;
            float mr = spow2[(k << 5) + 2 * n], mi = spow2[(k << 5) + 2 * n + 1];
            float nr2 = prr * mr - pii * mi;
            float ni2 = fmaf(prr, mi, pii * mr);
            prr = bit ? nr2 : prr;
            pii = bit ? ni2 : pii;
        }
        ptab[n * 128 + j * 2]     = prr;
        ptab[n * 128 + j * 2 + 1] = pii;
    }
    __syncthreads();

    // ---- E = V @ Xc ----
    f32x4 acc[2][4];
    #pragma unroll
    for (int mt = 0; mt < 2; mt++)
        #pragma unroll
        for (int nt = 0; nt < 4; nt++) acc[mt][nt] = (f32x4)(0.f);
    {
        s16x8 af[2], bfr[4];
        #pragma unroll
        for (int mt = 0; mt < 2; mt++)
            af[mt] = *(const s16x8*)&sM[(mt * 16 + ml) * 40 + kg * 8];
        #pragma unroll
        for (int nt = 0; nt < 4; nt++)
            bfr[nt] = *(const s16x8*)&sXc[(w * 64 + nt * 16 + ml) * 40 + kg * 8];
        #pragma unroll
        for (int mt = 0; mt < 2; mt++)
            #pragma unroll
            for (int nt = 0; nt < 4; nt++)
                acc[mt][nt] = __builtin_amdgcn_mfma_f32_16x16x32_bf16(af[mt], bfr[nt], acc[mt][nt], 0, 0, 0);
    }
    // ---- unpack E fragments -> per-thread zr/zi, two explicit 16-row passes ----
    float zr[16], zi[16];
    // pass 0: acc[0] rows 0..15
    #pragma unroll
    for (int nt = 0; nt < 4; nt++)
        #pragma unroll
        for (int r = 0; r < 4; r++)
            scratch[(kg * 4 + r) * 260 + (w * 64 + nt * 16 + ml)] = acc[0][nt][r];
    __syncthreads();
    #pragma unroll
    for (int q = 0; q < 8; q++) {
        zr[q] = scratch[(2 * q) * 260 + tid];
        zi[q] = scratch[(2 * q + 1) * 260 + tid];
    }
    __syncthreads();
    // pass 1: acc[1] rows 16..31
    #pragma unroll
    for (int nt = 0; nt < 4; nt++)
        #pragma unroll
        for (int r = 0; r < 4; r++)
            scratch[(kg * 4 + r) * 260 + (w * 64 + nt * 16 + ml)] = acc[1][nt][r];
    __syncthreads();
    #pragma unroll
    for (int q = 0; q < 8; q++) {
        zr[8 + q] = scratch[(2 * q) * 260 + tid];
        zi[8 + q] = scratch[(2 * q + 1) * 260 + tid];
    }

    // ---- in-wave inclusive scan (shuffles) ----
    __builtin_amdgcn_s_setprio(1);
    #pragma unroll 1
    for (int k = 0; k < 6; k++) {
        const int o = 1 << k;
        const bool act = lane >= o;
        #pragma unroll
        for (int n = 0; n < 16; n++) {
            float lr = __shfl(zr[n], lane - o);
            float li = __shfl(zi[n], lane - o);
            float mr = spow2[(k << 5) + 2 * n], mi = spow2[(k << 5) + 2 * n + 1];
            float nzr = fmaf(mr, lr, fmaf(-mi, li, zr[n]));
            float nzi = fmaf(mr, li, fmaf(mi, lr, zi[n]));
            zr[n] = act ? nzr : zr[n];
            zi[n] = act ? nzi : zi[n];
        }
    }
    if (lane == 63) {
        #pragma unroll
        for (int n = 0; n < 16; n++) {
            swc[w * 32 + 2 * n]     = zr[n];
            swc[w * 32 + 2 * n + 1] = zi[n];
        }
    }
    __syncthreads();
    float qr[16], qi[16];
    #pragma unroll
    for (int n = 0; n < 16; n++) { qr[n] = 0.f; qi[n] = 0.f; }
    #pragma unroll 1
    for (int a = 0; a < 3; a++) {
        if (a < w) {
            int p = w - 1 - a;
            #pragma unroll
            for (int n = 0; n < 16; n++) {
                float ar = swc[a * 32 + 2 * n], ai = swc[a * 32 + 2 * n + 1];
                float mr = 1.f, mi = 0.f;
                if (p > 0) { mr = spow2[((5 + p) << 5) + 2 * n]; mi = spow2[((5 + p) << 5) + 2 * n + 1]; }
                qr[n] = fmaf(mr, ar, fmaf(-mi, ai, qr[n]));
                qi[n] = fmaf(mr, ai, fmaf(mi, ar, qi[n]));
            }
        }
    }
    // final update: w32^lane from the block-shared table
    #pragma unroll
    for (int n = 0; n < 16; n++) {
        float2 pj = *(const float2*)&ptab[n * 128 + (lane << 1)];
        float pr = __shfl(zr[n], lane - 1);
        float pi = __shfl(zi[n], lane - 1);
        pr = (lane == 0) ? 0.f : pr;
        pi = (lane == 0) ? 0.f : pi;
        zr[n] = fmaf(pj.x, qr[n], fmaf(-pj.y, qi[n], pr));
        zi[n] = fmaf(pj.x, qi[n], fmaf(pj.y, qr[n], pi));
    }
    __builtin_amdgcn_s_setprio(0);
    {
        unsigned short* sCc = (unsigned short*)scratch;
        #pragma unroll
        for (int g = 0; g < 4; g++) {
            u16x8 pk;
            #pragma unroll
            for (int q = 0; q < 4; q++) {
                pk[2 * q]     = f2bf(zr[g * 4 + q]);
                pk[2 * q + 1] = f2bf(zi[g * 4 + q]);
            }
            *(u16x8*)&sCc[tid * 40 + g * 8] = pk;
        }
    }
    __syncthreads();

    // ---- y = TK @ Xc + G @ Cc ----
    #pragma unroll
    for (int mt = 0; mt < 2; mt++)
        #pragma unroll
        for (int nt = 0; nt < 4; nt++) acc[mt][nt] = (f32x4)(0.f);
    {
        const unsigned short* sCc = (const unsigned short*)scratch;
        s16x8 a1[2], a2[2], bfx[4], bfc[4];
        #pragma unroll
        for (int mt = 0; mt < 2; mt++) {
            a1[mt] = *(const s16x8*)&sM[1280 + (mt * 16 + ml) * 40 + kg * 8];
            a2[mt] = *(const s16x8*)&sM[2560 + (mt * 16 + ml) * 40 + kg * 8];
        }
        #pragma unroll
        for (int nt = 0; nt < 4; nt++) {
            bfx[nt] = *(const s16x8*)&sXc[(w * 64 + nt * 16 + ml) * 40 + kg * 8];
            bfc[nt] = *(const s16x8*)&sCc[(w * 64 + nt * 16 + ml) * 40 + kg * 8];
        }
        #pragma unroll
        for (int mt = 0; mt < 2; mt++)
            #pragma unroll
            for (int nt = 0; nt < 4; nt++) {
                acc[mt][nt] = __builtin_amdgcn_mfma_f32_16x16x32_bf16(a1[mt], bfx[nt], acc[mt][nt], 0, 0, 0);
                acc[mt][nt] = __builtin_amdgcn_mfma_f32_16x16x32_bf16(a2[mt], bfc[nt], acc[mt][nt], 0, 0, 0);
            }
    }
    // ---- output transpose + D-residual, two explicit 16-row passes (static idx) ----
    const float Dh = Dp[h];
    u16x8* yp = (u16x8*)(yout + ((size_t)bh << 13) + (tid << 5));
    // pass 0: acc[0] -> y rows 0..15 (output groups g=0,1)
    __syncthreads();   // sCc MFMA reads done before overwrite
    #pragma unroll
    for (int nt = 0; nt < 4; nt++)
        #pragma unroll
        for (int r = 0; r < 4; r++)
            scratch[(kg * 4 + r) * 260 + (w * 64 + nt * 16 + ml)] = acc[0][nt][r];
    __syncthreads();
    #pragma unroll
    for (int g = 0; g < 2; g++) {
        u16x8 pk;
        #pragma unroll
        for (int e = 0; e < 8; e++) {
            int i = g * 8 + e;
            pk[e] = f2bf(fmaf(Dh, xr[i], scratch[i * 260 + tid]));
        }
        yp[g] = pk;
    }
    // pass 1: acc[1] -> y rows 16..31 (output groups g=2,3)
    __syncthreads();
    #pragma unroll
    for (int nt = 0; nt < 4; nt++)
        #pragma unroll
        for (int r = 0; r < 4; r++)
            scratch[(kg * 4 + r) * 260 + (w * 64 + nt * 16 + ml)] = acc[1][nt][r];
    __syncthreads();
    #pragma unroll
    for (int g = 2; g < 4; g++) {
        u16x8 pk;
        #pragma unroll
        for (int e = 0; e < 8; e++) {
            int i = g * 8 + e;
            pk[e] = f2bf(fmaf(Dh, xr[i], scratch[(i - 16) * 260 + tid]));
        }
        yp[g] = pk;
    }
}

// ============ kernel 3: transpose y[bh][g] -> yT[b][g][h] ============
__global__ __launch_bounds__(256) void ytrans(const unsigned short* __restrict__ y,
                                              unsigned short* __restrict__ yT)
{
    __shared__ unsigned short sT[128 * 72];
    const int b = blockIdx.y, g0 = blockIdx.x << 6;
    const int tid = threadIdx.x;
    #pragma unroll
    for (int j = 0; j < 4; j++) {
        int li = tid + (j << 8);
        int h = li >> 3, g8 = (li & 7) << 3;
        u16x8 v = *(const u16x8*)(y + (((size_t)(b * 128 + h)) << 13) + g0 + g8);
        int gp = (g8 + (((h >> 3) & 7) << 3)) & 63;
        *(u16x8*)&sT[h * 72 + gp] = v;
    }
    __syncthreads();
    #pragma unroll
    for (int j = 0; j < 4; j++) {
        int li = tid + (j << 8);
        int g = li >> 4, h8 = (li & 15) << 3;
        u16x8 o;
        #pragma unroll
        for (int e = 0; e < 8; e++) {
            int h = h8 + e;
            int gp = (g + (((h >> 3) & 7) << 3)) & 63;
            o[e] = sT[h * 72 + gp];
        }
        *(u16x8*)(yT + (((size_t)(b * 8192 + g0 + g)) << 7) + h8) = o;
    }
}

// ============ kernel 4: MFMA dilated conv + bias + LeakyReLU + fused BN stats ============
__global__ __launch_bounds__(256) void conv_mfma(
    const unsigned short* __restrict__ yT,
    const unsigned short* __restrict__ WB,
    const float* __restrict__ b1, const float* __restrict__ b2,
    const float* __restrict__ b3, const float* __restrict__ b4,
    unsigned short* __restrict__ z,
    float* __restrict__ gstats)
{
    __shared__ unsigned short sW[2][128 * 40];
    __shared__ unsigned short sY[2][128 * 40];
    __shared__ float sS1[128];
    __shared__ float sS2[128];
    const int tid = threadIdx.x;
    const int lane = tid & 63, w = tid >> 6;
    const int branch = blockIdx.y, b = blockIdx.z;
    const int t0 = blockIdx.x << 7;
    const int d = 1 << branch;
    const int coH = (w & 1) << 6, tH = (w >> 1) << 6;
    const int ml = lane & 15, kg = lane >> 4;

    if (tid < 128) { sS1[tid] = 0.f; sS2[tid] = 0.f; }

    f32x4 acc[4][4];
    #pragma unroll
    for (int mt = 0; mt < 4; mt++)
        #pragma unroll
        for (int nt = 0; nt < 4; nt++) acc[mt][nt] = (f32x4)(0.f);

    const unsigned short* WBb = WB + (size_t)branch * 49152;

    const int wco0 = tid >> 2,        wkq0 = (tid & 3) << 3;
    const int wco1 = (tid + 256) >> 2, wkq1 = (tid & 3) << 3;

    auto loadY = [&](int li, int kc) -> u16x8 {
        const int tap = kc >> 2, hc = (kc & 3) << 5;
        const int goff = d * (tap - 1);
        int n = li >> 2, kq = (li & 3) << 3;
        int g = ((t0 + n) << 2) + goff;
        u16x8 v;
        if ((unsigned)g < 8192u) {
            v = *(const u16x8*)(yT + (((size_t)(b * 8192 + g)) << 7) + hc + kq);
        } else {
            #pragma unroll
            for (int e = 0; e < 8; e++) v[e] = 0;
        }
        return v;
    };
    auto loadW = [&](int co, int kq, int kc) -> u16x8 {
        return *(const u16x8*)(WBb + (size_t)co * 384 + (kc << 5) + kq);
    };

    // ---- prologue: stage kc=0 into buffer 0 ----
    {
        u16x8 vw0 = loadW(wco0, wkq0, 0);
        u16x8 vw1 = loadW(wco1, wkq1, 0);
        u16x8 vy0 = loadY(tid, 0);
        u16x8 vy1 = loadY(tid + 256, 0);
        *(u16x8*)&sW[0][wco0 * 40 + wkq0] = vw0;
        *(u16x8*)&sW[0][wco1 * 40 + wkq1] = vw1;
        *(u16x8*)&sY[0][(tid >> 2) * 40 + ((tid & 3) << 3)] = vy0;
        *(u16x8*)&sY[0][((tid + 256) >> 2) * 40 + ((tid & 3) << 3)] = vy1;
    }

    #pragma unroll 1
    for (int kc = 0; kc < 12; kc++) {
        const int cur = kc & 1;
        __syncthreads();

        u16x8 nw0, nw1, ny0, ny1;
        const bool more = (kc + 1 < 12);
        if (more) {
            nw0 = loadW(wco0, wkq0, kc + 1);
            nw1 = loadW(wco1, wkq1, kc + 1);
            ny0 = loadY(tid, kc + 1);
            ny1 = loadY(tid + 256, kc + 1);
        }

        s16x8 af[4], bfr[4];
        #pragma unroll
        for (int mt = 0; mt < 4; mt++)
            af[mt] = *(const s16x8*)&sW[cur][(coH + mt * 16 + ml) * 40 + (kg << 3)];
        #pragma unroll
        for (int nt = 0; nt < 4; nt++)
            bfr[nt] = *(const s16x8*)&sY[cur][(tH + nt * 16 + ml) * 40 + (kg << 3)];
        #pragma unroll
        for (int mt = 0; mt < 4; mt++)
            #pragma unroll
            for (int nt = 0; nt < 4; nt++)
                acc[mt][nt] = __builtin_amdgcn_mfma_f32_16x16x32_bf16(af[mt], bfr[nt], acc[mt][nt], 0, 0, 0);

        if (more) {
            *(u16x8*)&sW[cur ^ 1][wco0 * 40 + wkq0] = nw0;
            *(u16x8*)&sW[cur ^ 1][wco1 * 40 + wkq1] = nw1;
            *(u16x8*)&sY[cur ^ 1][(tid >> 2) * 40 + ((tid & 3) << 3)] = ny0;
            *(u16x8*)&sY[cur ^ 1][((tid + 256) >> 2) * 40 + ((tid & 3) << 3)] = ny1;
        }
    }

    const float* bp = (branch == 0) ? b1 : (branch == 1) ? b2 : (branch == 2) ? b3 : b4;
    #pragma unroll
    for (int mt = 0; mt < 4; mt++) {
        #pragma unroll
        for (int r = 0; r < 4; r++) {
            const int co = coH + mt * 16 + (kg << 2) + r;
            const float bb = bp[co];
            float ls1 = 0.f, ls2 = 0.f;
            #pragma unroll
            for (int nt = 0; nt < 4; nt++) {
                const int t = t0 + tH + nt * 16 + ml;
                float v = acc[mt][nt][r] + bb;
                if (branch != 0) v = (v >= 0.f) ? v : 0.3f * v;
                ls1 += v;
                ls2 = fmaf(v, v, ls2);
                z[(((size_t)((branch * 16 + b) * 128 + co)) << 11) + t] = f2bf(v);
            }
            #pragma unroll
            for (int o = 8; o > 0; o >>= 1) {
                ls1 += __shfl_down(ls1, o, 16);
                ls2 += __shfl_down(ls2, o, 16);
            }
            if (ml == 0) {
                atomicAdd(&sS1[co], ls1);
                atomicAdd(&sS2[co], ls2);
            }
        }
    }
    __syncthreads();
    if (tid < 128) {
        atomicAdd(&gstats[(((size_t)branch << 7) + tid) * 2],     sS1[tid]);
        atomicAdd(&gstats[(((size_t)branch << 7) + tid) * 2 + 1], sS2[tid]);
    }
}

// ============ kernel 5: BN affine apply (finalizes raw sums inline, fp32 out) ============
__global__ __launch_bounds__(256) void bn_apply(const unsigned short* __restrict__ z,
                                                const float* __restrict__ stats,
                                                const float* __restrict__ gam,
                                                const float* __restrict__ bet,
                                                float* __restrict__ out)
{
    const size_t idx = (((size_t)blockIdx.x << 8) + threadIdx.x) << 3;
    const int t = (int)(idx & 2047);
    const size_t bc = idx >> 11;
    const int ch = (int)(bc & 511);
    const int b = (int)(bc >> 9);
    const int branch = ch >> 7, co = ch & 127;
    const float s1 = stats[ch * 2], s2 = stats[ch * 2 + 1];
    const float m = s1 * (1.0f / 32768.0f);
    const float var = fmaf(-m, m, s2 * (1.0f / 32768.0f));
    const float inv = 1.0f / sqrtf(var + 1e-5f);
    const float ga = gam[co], be = bet[co];
    const float sc = ga * inv, sh = fmaf(-m, sc, be);
    const unsigned short* zp = z + (((size_t)((branch * 16 + b) * 128 + co)) << 11) + t;
    u16x8 v = *(const u16x8*)zp;
    float4 o0, o1;
    o0.x = fmaf(bf2f(v[0]), sc, sh); o0.y = fmaf(bf2f(v[1]), sc, sh);
    o0.z = fmaf(bf2f(v[2]), sc, sh); o0.w = fmaf(bf2f(v[3]), sc, sh);
    o1.x = fmaf(bf2f(v[4]), sc, sh); o1.y = fmaf(bf2f(v[5]), sc, sh);
    o1.z = fmaf(bf2f(v[6]), sc, sh); o1.w = fmaf(bf2f(v[7]), sc, sh);
    *(float4*)(out + idx)     = o0;
    *(float4*)(out + idx + 4) = o1;
}

extern "C" void kernel_launch(void* const* d_in, const int* in_sizes, int n_in,
                              void* d_out, int out_size, void* d_ws, size_t ws_size,
                              hipStream_t stream) {
    const float* x      = (const float*)d_in[0];
    const float* log_dt = (const float*)d_in[1];
    const float* A_log  = (const float*)d_in[2];
    const float* A_imag = (const float*)d_in[3];
    const float* B_re   = (const float*)d_in[4];
    const float* B_im   = (const float*)d_in[5];
    const float* C_re   = (const float*)d_in[6];
    const float* C_im   = (const float*)d_in[7];
    const float* Dp     = (const float*)d_in[8];
    const float* w1 = (const float*)d_in[9];
    const float* b1 = (const float*)d_in[10];
    const float* w2 = (const float*)d_in[11];
    const float* b2 = (const float*)d_in[12];
    const float* w3 = (const float*)d_in[13];
    const float* b3 = (const float*)d_in[14];
    const float* w4 = (const float*)d_in[15];
    const float* b4 = (const float*)d_in[16];
    const float* gam = (const float*)d_in[17];
    const float* bet = (const float*)d_in[18];

    float* w32p = (float*)d_ws;
    unsigned short* MATSp = (unsigned short*)((char*)d_ws + MATS_OFF);
    unsigned short* WBp = (unsigned short*)((char*)d_ws + WB_OFF);
    float* stats = (float*)((char*)d_ws + STAT_OFF);
    unsigned short* yws = (unsigned short*)((char*)d_ws + Y_OFF);
    unsigned short* yT  = (unsigned short*)((char*)d_ws + YT_OFF);
    unsigned short* zws = (unsigned short*)((char*)d_ws + Z_OFF);
    float* out = (float*)d_out;

    prep<<<dim3(896), dim3(256), 0, stream>>>(log_dt, A_log, A_imag, B_re, B_im, C_re, C_im,
                                              w32p, MATSp, w1, w2, w3, w4, WBp, stats);
    s4d_mfma<<<dim3(2048), dim3(256), 0, stream>>>(x, w32p, MATSp, Dp, yws);
    ytrans<<<dim3(128, 16), dim3(256), 0, stream>>>(yws, yT);
    conv_mfma<<<dim3(16, 4, 16), dim3(256), 0, stream>>>(yT, WBp, b1, b2, b3, b4, zws, stats);
    bn_apply<<<dim3(8192), dim3(256), 0, stream>>>(zws, stats, gam, bet, out);
}